// Round 1
// baseline (5665.929 us; speedup 1.0000x reference)
//
#include <hip/hip_runtime.h>
#include <cstdint>

#define Bq 64
#define Pq 196
#define ENCq 2048
#define Aq 512
#define Hq 512
#define Eq 512
#define Vq 30000
#define Lq 30
#define Tq 29

__device__ __forceinline__ float sigmoidf_(float x){ return 1.0f/(1.0f+expf(-x)); }

// ---------------- sort (stable descending argsort of lengths) ----------------
__global__ void sort_kernel(const int* __restrict__ cap_len, const int* __restrict__ caps,
                            int* __restrict__ sort_ind_i, int* __restrict__ dec_len_i,
                            int* __restrict__ caps_sorted,
                            float* __restrict__ out_caps, float* __restrict__ out_declen,
                            float* __restrict__ out_sortind)
{
    __shared__ int len[Bq];
    __shared__ int sidx[Bq];
    int i = threadIdx.x;
    len[i] = cap_len[i];
    __syncthreads();
    int li = len[i];
    int rank = 0;
    for (int j = 0; j < Bq; j++){
        int lj = len[j];
        rank += (lj > li) || (lj == li && j < i);
    }
    sidx[rank] = i;
    __syncthreads();
    int src = sidx[i];
    sort_ind_i[i] = src;
    int dl = len[src] - 1;
    dec_len_i[i] = dl;
    out_declen[i] = (float)dl;
    out_sortind[i] = (float)src;
    for (int tt = 0; tt < Lq; tt++){
        int cv = caps[src*Lq + tt];
        caps_sorted[i*Lq + tt] = cv;
        out_caps[i*Lq + tt] = (float)cv;
    }
}

// ---------------- small packing helpers ----------------
__global__ void pack_rowcat(float* __restrict__ dst, const float* __restrict__ a, int na,
                            const float* __restrict__ b, int nb)
{
    int i = blockIdx.x*256 + threadIdx.x;
    if (i < na) dst[i] = a[i];
    else if (i < na + nb) dst[i] = b[i - na];
}

__global__ void pack_colcat(float* __restrict__ dst, const float* __restrict__ a,
                            const float* __restrict__ b)
{
    int i = blockIdx.x*256 + threadIdx.x;
    if (i >= 2048*3072) return;
    int r = i / 3072, c = i % 3072;
    dst[i] = (c < 2560) ? a[(size_t)r*2560 + c] : b[(size_t)r*512 + (c - 2560)];
}

__global__ void biasg_kernel(float* __restrict__ dst, const float* __restrict__ bi,
                             const float* __restrict__ bh)
{
    int i = blockIdx.x*256 + threadIdx.x;
    if (i < 2048) dst[i] = bi[i] + bh[i];
}

__global__ void zero_kernel(float* __restrict__ p, int n)
{
    int i = blockIdx.x*256 + threadIdx.x;
    if (i < n) p[i] = 0.f;
}

// ---------------- mean over P of sorted encoder ----------------
__global__ void mean_enc_kernel(const float* __restrict__ enc, const int* __restrict__ sort_ind,
                                float* __restrict__ mean_enc)
{
    int b = blockIdx.x;
    int src = sort_ind[b];
    const float* base = enc + (size_t)src * Pq * ENCq;
    for (int d = threadIdx.x; d < ENCq; d += 256){
        float s = 0.f;
        for (int p = 0; p < Pq; p++) s += base[(size_t)p*ENCq + d];
        mean_enc[(size_t)b*ENCq + d] = s * (1.0f/196.0f);
    }
}

// ---------------- generic fp32 GEMM: C[m,n] = sum_k A[m,k]*W[n,k] (+bias) ----------------
// BM=BN=64, BK=32, 256 threads, each thread 4x4 micro-tile.
// atomic_mode: accumulate partial K-chunk via atomicAdd (bias added by z==0 chunk).
// mask_len (direct mode only): if t >= mask_len[m], write 0.
__global__ __launch_bounds__(256)
void gemm_k(const float* __restrict__ A, int lda,
            const float* __restrict__ W, int ldw,
            const float* __restrict__ bias,
            float* __restrict__ C, int ldc,
            int M, int N, int K, int kchunk, int atomic_mode,
            const int* __restrict__ mask_len, int t)
{
    __shared__ float As[32][68];
    __shared__ float Ws[32][68];
    const int tid = threadIdx.x;
    const int m0 = blockIdx.x * 64;
    const int n0 = blockIdx.y * 64;
    const int k0 = blockIdx.z * kchunk;
    int kend = k0 + kchunk; if (kend > K) kend = K;
    const int tm = (tid >> 4) << 2;   // 0..60 row offset
    const int tx = (tid & 15) << 2;   // 0..60 col offset
    const int lr = tid >> 2;          // 0..63 (load row)
    const int lc = (tid & 3) << 2;    // 0,4,8,12 (load k offset)
    float acc[4][4] = {{0}};

    for (int kt = k0; kt < kend; kt += 32){
        {
            int m = m0 + lr;
            float4 v0 = make_float4(0,0,0,0), v1 = make_float4(0,0,0,0);
            if (m < M){
                const float* ap = A + (size_t)m * lda + kt + lc;
                v0 = *(const float4*)ap;
                v1 = *(const float4*)(ap + 16);
            }
            As[lc+0][lr]=v0.x; As[lc+1][lr]=v0.y; As[lc+2][lr]=v0.z; As[lc+3][lr]=v0.w;
            As[lc+16][lr]=v1.x; As[lc+17][lr]=v1.y; As[lc+18][lr]=v1.z; As[lc+19][lr]=v1.w;
        }
        {
            int n = n0 + lr;
            float4 v0 = make_float4(0,0,0,0), v1 = make_float4(0,0,0,0);
            if (n < N){
                const float* wp = W + (size_t)n * ldw + kt + lc;
                v0 = *(const float4*)wp;
                v1 = *(const float4*)(wp + 16);
            }
            Ws[lc+0][lr]=v0.x; Ws[lc+1][lr]=v0.y; Ws[lc+2][lr]=v0.z; Ws[lc+3][lr]=v0.w;
            Ws[lc+16][lr]=v1.x; Ws[lc+17][lr]=v1.y; Ws[lc+18][lr]=v1.z; Ws[lc+19][lr]=v1.w;
        }
        __syncthreads();
        #pragma unroll
        for (int kk = 0; kk < 32; kk++){
            float a0=As[kk][tm+0], a1=As[kk][tm+1], a2=As[kk][tm+2], a3=As[kk][tm+3];
            float w0=Ws[kk][tx+0], w1=Ws[kk][tx+1], w2=Ws[kk][tx+2], w3=Ws[kk][tx+3];
            acc[0][0]+=a0*w0; acc[0][1]+=a0*w1; acc[0][2]+=a0*w2; acc[0][3]+=a0*w3;
            acc[1][0]+=a1*w0; acc[1][1]+=a1*w1; acc[1][2]+=a1*w2; acc[1][3]+=a1*w3;
            acc[2][0]+=a2*w0; acc[2][1]+=a2*w1; acc[2][2]+=a2*w2; acc[2][3]+=a2*w3;
            acc[3][0]+=a3*w0; acc[3][1]+=a3*w1; acc[3][2]+=a3*w2; acc[3][3]+=a3*w3;
        }
        __syncthreads();
    }

    const bool addb = (bias != nullptr) && (blockIdx.z == 0);
    if (atomic_mode){
        #pragma unroll
        for (int i = 0; i < 4; i++){
            int m = m0 + tm + i;
            if (m >= M) continue;
            #pragma unroll
            for (int j = 0; j < 4; j++){
                int n = n0 + tx + j;
                if (n >= N) continue;
                float v = acc[i][j];
                if (addb) v += bias[n];
                atomicAdd(&C[(size_t)m*ldc + n], v);
            }
        }
    } else {
        #pragma unroll
        for (int i = 0; i < 4; i++){
            int m = m0 + tm + i;
            if (m >= M) continue;
            bool masked = (mask_len != nullptr) && (t >= mask_len[m]);
            #pragma unroll
            for (int j = 0; j < 4; j++){
                int n = n0 + tx + j;
                if (n >= N) continue;
                float v = acc[i][j];
                if (bias) v += bias[n];
                if (masked) v = 0.f;
                C[(size_t)m*ldc + n] = v;
            }
        }
    }
}

// ---------------- attention scores + softmax (one block per sorted b) ----------------
__global__ __launch_bounds__(256)
void attn_kernel(const float* __restrict__ att1,
                 const float* __restrict__ att2gate,  // [64][2560], cols 0..511 = att2
                 const float* __restrict__ faw, const float* __restrict__ fab,
                 const int* __restrict__ sort_ind,
                 const int* __restrict__ dec_len,
                 float* __restrict__ alpha_ws,
                 float* __restrict__ alphas_out, int t)
{
    __shared__ float a2s[Aq];
    __shared__ float fws[Aq];
    __shared__ float es[Pq];
    __shared__ float red[8];
    int b = blockIdx.x;
    int tid = threadIdx.x;
    for (int j = tid; j < Aq; j += 256){
        a2s[j] = att2gate[(size_t)b*2560 + j];
        fws[j] = faw[j];
    }
    __syncthreads();
    int src = sort_ind[b];
    const float* a1b = att1 + (size_t)src * Pq * Aq;
    int wid = tid >> 6, lane = tid & 63;
    float fb = fab[0];
    for (int p = wid; p < Pq; p += 4){
        const float* row = a1b + (size_t)p * Aq;
        float s = 0.f;
        #pragma unroll
        for (int i = 0; i < 8; i++){
            int a = lane + i*64;
            float v = row[a] + a2s[a];
            v = v > 0.f ? v : 0.f;
            s += v * fws[a];
        }
        #pragma unroll
        for (int off = 32; off; off >>= 1) s += __shfl_xor(s, off);
        if (lane == 0) es[p] = s + fb;
    }
    __syncthreads();
    float v = (tid < Pq) ? es[tid] : -3.4e38f;
    float m = v;
    #pragma unroll
    for (int off = 32; off; off >>= 1) m = fmaxf(m, __shfl_xor(m, off));
    if ((tid & 63) == 0) red[tid >> 6] = m;
    __syncthreads();
    float bm = fmaxf(fmaxf(red[0], red[1]), fmaxf(red[2], red[3]));
    float ex = (tid < Pq) ? expf(v - bm) : 0.f;
    float s = ex;
    #pragma unroll
    for (int off = 32; off; off >>= 1) s += __shfl_xor(s, off);
    if ((tid & 63) == 0) red[4 + (tid >> 6)] = s;
    __syncthreads();
    float bs = red[4] + red[5] + red[6] + red[7];
    if (tid < Pq){
        float al = ex / bs;
        alpha_ws[b*Pq + tid] = al;
        float mask = (t < dec_len[b]) ? 1.f : 0.f;
        alphas_out[((size_t)b*Tq + t)*Pq + tid] = al * mask;
    }
}

// ---------------- awe = gate * (alpha @ enc), builds x_cat = [emb | awe | h] ----------------
__global__ __launch_bounds__(256)
void awe_xcat_kernel(const float* __restrict__ enc,
                     const float* __restrict__ att2gate,  // cols 512..2559 = gate pre-sigmoid
                     const float* __restrict__ alpha_ws,
                     const float* __restrict__ embed,
                     const float* __restrict__ hc,
                     const int* __restrict__ sort_ind,
                     const int* __restrict__ caps_sorted,
                     float* __restrict__ xcat, int t)
{
    int b = blockIdx.x, y = blockIdx.y, tid = threadIdx.x;
    __shared__ float als[Pq];
    if (tid < Pq) als[tid] = alpha_ws[b*Pq + tid];
    __syncthreads();
    int src = sort_ind[b];
    int d = y*256 + tid;
    const float* ebase = enc + (size_t)src * Pq * ENCq + d;
    float s = 0.f;
    for (int p = 0; p < Pq; p++) s += als[p] * ebase[(size_t)p*ENCq];
    float g = sigmoidf_(att2gate[(size_t)b*2560 + 512 + d]);
    xcat[(size_t)b*3072 + 512 + d] = g * s;
    if (y == 0){
        int cap = caps_sorted[b*Lq + t];
        const float* er = embed + (size_t)cap*Eq;
        for (int j = tid; j < Eq; j += 256) xcat[(size_t)b*3072 + j] = er[j];
    } else if (y == 1){
        for (int j = tid; j < Hq; j += 256) xcat[(size_t)b*3072 + 2560 + j] = hc[b*1024 + j];
    }
}

// ---------------- LSTM cell elementwise (in-place h,c update) ----------------
__global__ void lstm_kernel(const float* __restrict__ gates, float* __restrict__ hc)
{
    int idx = blockIdx.x*256 + threadIdx.x;
    if (idx >= Bq*Hq) return;
    int b = idx >> 9, j = idx & 511;
    const float* g = gates + (size_t)b*2048;
    float gi = sigmoidf_(g[j]);
    float gf = sigmoidf_(g[512 + j]);
    float gg = tanhf(g[1024 + j]);
    float go = sigmoidf_(g[1536 + j]);
    float c = hc[b*1024 + 512 + j];
    float cn = gf*c + gi*gg;
    float hn = go * tanhf(cn);
    hc[b*1024 + 512 + j] = cn;
    hc[b*1024 + j] = hn;
}

extern "C" void kernel_launch(void* const* d_in, const int* in_sizes, int n_in,
                              void* d_out, int out_size, void* d_ws, size_t ws_size,
                              hipStream_t stream)
{
    const float* encoder_out = (const float*)d_in[0];
    const float* enc_att_w   = (const float*)d_in[1];
    const float* enc_att_b   = (const float*)d_in[2];
    const float* dec_att_w   = (const float*)d_in[3];
    const float* dec_att_b   = (const float*)d_in[4];
    const float* full_att_w  = (const float*)d_in[5];
    const float* full_att_b  = (const float*)d_in[6];
    const float* embed       = (const float*)d_in[7];
    const float* W_ih        = (const float*)d_in[8];
    const float* W_hh        = (const float*)d_in[9];
    const float* b_ih        = (const float*)d_in[10];
    const float* b_hh        = (const float*)d_in[11];
    const float* init_h_w    = (const float*)d_in[12];
    const float* init_h_b    = (const float*)d_in[13];
    const float* init_c_w    = (const float*)d_in[14];
    const float* init_c_b    = (const float*)d_in[15];
    const float* f_beta_w    = (const float*)d_in[16];
    const float* f_beta_b    = (const float*)d_in[17];
    const float* fc_w        = (const float*)d_in[18];
    const float* fc_b        = (const float*)d_in[19];
    const int*   enc_caps    = (const int*)d_in[20];
    const int*   cap_len     = (const int*)d_in[21];

    float* out_preds   = (float*)d_out;                       // 64*29*30000
    float* out_caps    = out_preds + (size_t)Bq*Tq*Vq;        // 64*30
    float* out_declen  = out_caps + Bq*Lq;                    // 64
    float* out_alphas  = out_declen + Bq;                     // 64*29*196
    float* out_sortind = out_alphas + (size_t)Bq*Tq*Pq;       // 64

    float* ws = (float*)d_ws;
    float* att1      = ws;                        // 12544*512
    float* whc       = att1 + 6422528;            // 1024*2048
    float* bias_hc   = whc + 2097152;             // 1024
    float* wcat2     = bias_hc + 1024;            // 2560*512
    float* bias2     = wcat2 + 1310720;           // 2560
    float* wcatg     = bias2 + 2560;              // 2048*3072
    float* bias_g    = wcatg + 6291456;           // 2048
    float* mean_enc  = bias_g + 2048;             // 64*2048
    float* hc        = mean_enc + 131072;         // 64*1024 (h | c)
    float* att2gate  = hc + 65536;                // 64*2560
    float* alpha_ws  = att2gate + 163840;         // 64*196
    float* xcat      = alpha_ws + 12544;          // 64*3072
    float* gatesb    = xcat + 196608;             // 64*2048
    int* caps_sorted = (int*)(gatesb + 131072);   // 64*30
    int* sort_ind_i  = caps_sorted + Bq*Lq;       // 64
    int* dec_len_i   = sort_ind_i + Bq;           // 64

    // ---- setup ----
    sort_kernel<<<1, 64, 0, stream>>>(cap_len, enc_caps, sort_ind_i, dec_len_i,
                                      caps_sorted, out_caps, out_declen, out_sortind);

    pack_rowcat<<<(2097152+255)/256, 256, 0, stream>>>(whc, init_h_w, 1048576, init_c_w, 1048576);
    pack_rowcat<<<(1024+255)/256, 256, 0, stream>>>(bias_hc, init_h_b, 512, init_c_b, 512);
    pack_rowcat<<<(1310720+255)/256, 256, 0, stream>>>(wcat2, dec_att_w, 262144, f_beta_w, 1048576);
    pack_rowcat<<<(2560+255)/256, 256, 0, stream>>>(bias2, dec_att_b, 512, f_beta_b, 2048);
    pack_colcat<<<(6291456+255)/256, 256, 0, stream>>>(wcatg, W_ih, W_hh);
    biasg_kernel<<<8, 256, 0, stream>>>(bias_g, b_ih, b_hh);

    mean_enc_kernel<<<64, 256, 0, stream>>>(encoder_out, sort_ind_i, mean_enc);

    // h0/c0: M=64, N=1024, K=2048, split-K (4 chunks of 512)
    zero_kernel<<<(65536+255)/256, 256, 0, stream>>>(hc, 65536);
    gemm_k<<<dim3(1,16,4), 256, 0, stream>>>(mean_enc, 2048, whc, 2048, bias_hc,
                                             hc, 1024, 64, 1024, 2048, 512, 1, nullptr, 0);

    // att1: M=12544 (original b order), N=512, K=2048, direct
    gemm_k<<<dim3(196,8,1), 256, 0, stream>>>(encoder_out, 2048, enc_att_w, 2048, enc_att_b,
                                              att1, 512, 12544, 512, 2048, 2048, 0, nullptr, 0);

    for (int t = 0; t < Tq; t++){
        // att2|gate: M=64, N=2560, K=512, split-K (4 chunks of 128)
        zero_kernel<<<(163840+255)/256, 256, 0, stream>>>(att2gate, 163840);
        gemm_k<<<dim3(1,40,4), 256, 0, stream>>>(hc, 1024, wcat2, 512, bias2,
                                                 att2gate, 2560, 64, 2560, 512, 128, 1, nullptr, 0);

        attn_kernel<<<64, 256, 0, stream>>>(att1, att2gate, full_att_w, full_att_b,
                                            sort_ind_i, dec_len_i, alpha_ws, out_alphas, t);

        awe_xcat_kernel<<<dim3(64,8), 256, 0, stream>>>(encoder_out, att2gate, alpha_ws, embed,
                                                        hc, sort_ind_i, caps_sorted, xcat, t);

        // gates: M=64, N=2048, K=3072, split-K (12 chunks of 256)
        zero_kernel<<<(131072+255)/256, 256, 0, stream>>>(gatesb, 131072);
        gemm_k<<<dim3(1,32,12), 256, 0, stream>>>(xcat, 3072, wcatg, 3072, bias_g,
                                                  gatesb, 2048, 64, 2048, 3072, 256, 1, nullptr, 0);

        lstm_kernel<<<(Bq*Hq+255)/256, 256, 0, stream>>>(gatesb, hc);

        // preds: M=64, N=30000, K=512, direct, masked epilogue
        gemm_k<<<dim3(1,469,1), 256, 0, stream>>>(hc, 1024, fc_w, 512, fc_b,
                                                  out_preds + (size_t)t*Vq, (size_t)Tq*Vq,
                                                  64, Vq, 512, 512, 0, dec_len_i, t);
    }
}

// Round 2
// 3655.557 us; speedup vs baseline: 1.5499x; 1.5499x over previous
//
#include <hip/hip_runtime.h>
#include <hip/hip_bf16.h>
#include <cstdint>

#define Bq 64
#define Pq 196
#define ENCq 2048
#define Aq 512
#define Hq 512
#define Vq 30000
#define Lq 30
#define Tq 29

typedef __bf16 bf16x8 __attribute__((ext_vector_type(8)));
typedef float f32x4 __attribute__((ext_vector_type(4)));
typedef __hip_bfloat16 bf16_t;

__device__ __forceinline__ float sigmoidf_(float x){ return 1.0f/(1.0f+expf(-x)); }

// ---------------- sort (stable descending argsort of lengths) ----------------
__global__ void sort_kernel(const int* __restrict__ cap_len, const int* __restrict__ caps,
                            int* __restrict__ sort_ind_i, int* __restrict__ dec_len_i,
                            int* __restrict__ caps_sorted,
                            float* __restrict__ out_caps, float* __restrict__ out_declen,
                            float* __restrict__ out_sortind)
{
    __shared__ int len[Bq];
    __shared__ int sidx[Bq];
    int i = threadIdx.x;
    len[i] = cap_len[i];
    __syncthreads();
    int li = len[i];
    int rank = 0;
    for (int j = 0; j < Bq; j++){
        int lj = len[j];
        rank += (lj > li) || (lj == li && j < i);
    }
    sidx[rank] = i;
    __syncthreads();
    int src = sidx[i];
    sort_ind_i[i] = src;
    int dl = len[src] - 1;
    dec_len_i[i] = dl;
    out_declen[i] = (float)dl;
    out_sortind[i] = (float)src;
    for (int tt = 0; tt < Lq; tt++){
        int cv = caps[src*Lq + tt];
        caps_sorted[i*Lq + tt] = cv;
        out_caps[i*Lq + tt] = (float)cv;
    }
}

// ---------------- pack / convert helpers ----------------
__global__ void cvt_bf16(bf16_t* __restrict__ dst, const float* __restrict__ src, int n)
{
    int i = blockIdx.x*256 + threadIdx.x;
    if (i < n) dst[i] = __float2bfloat16(src[i]);
}

__global__ void pack_rowcat_bf16(bf16_t* __restrict__ dst, const float* __restrict__ a, int na,
                                 const float* __restrict__ b, int nb)
{
    int i = blockIdx.x*256 + threadIdx.x;
    if (i < na) dst[i] = __float2bfloat16(a[i]);
    else if (i < na + nb) dst[i] = __float2bfloat16(b[i - na]);
}

__global__ void pack_rowcat_f32(float* __restrict__ dst, const float* __restrict__ a, int na,
                                const float* __restrict__ b, int nb)
{
    int i = blockIdx.x*256 + threadIdx.x;
    if (i < na) dst[i] = a[i];
    else if (i < na + nb) dst[i] = b[i - na];
}

__global__ void pack_colcat_bf16(bf16_t* __restrict__ dst, const float* __restrict__ a,
                                 const float* __restrict__ b)
{
    int i = blockIdx.x*256 + threadIdx.x;
    if (i >= 2048*3072) return;
    int r = i / 3072, c = i % 3072;
    float v = (c < 2560) ? a[(size_t)r*2560 + c] : b[(size_t)r*512 + (c - 2560)];
    dst[i] = __float2bfloat16(v);
}

__global__ void biasg_kernel(float* __restrict__ dst, const float* __restrict__ bi,
                             const float* __restrict__ bh)
{
    int i = blockIdx.x*256 + threadIdx.x;
    if (i < 2048) dst[i] = bi[i] + bh[i];
}

// ---------------- mean over P of sorted encoder (bf16 out) ----------------
__global__ void mean_enc_kernel(const float* __restrict__ enc, const int* __restrict__ sort_ind,
                                bf16_t* __restrict__ mean_enc)
{
    int b = blockIdx.x;
    int d = blockIdx.y*256 + threadIdx.x;
    int src = sort_ind[b];
    const float* base = enc + (size_t)src * Pq * ENCq + d;
    float s = 0.f;
    for (int p = 0; p < Pq; p++) s += base[(size_t)p*ENCq];
    mean_enc[(size_t)b*ENCq + d] = __float2bfloat16(s * (1.0f/196.0f));
}

// ---------------- h0 -> bf16 ----------------
__global__ void h0_cvt(const float* __restrict__ hc, bf16_t* __restrict__ hb)
{
    int i = blockIdx.x*256 + threadIdx.x;
    if (i >= Bq*Hq) return;
    int b = i >> 9, j = i & 511;
    hb[i] = __float2bfloat16(hc[b*1024 + j]);
}

// ================= MFMA GEMM, waves split N =================
// C[m,n] = sum_k A[m,k] * W[n,k] + bias[n].  M = gridDim.x*64 exact.
// blockDim = 64*waves; wave w covers n-range (blockIdx.y*waves + w)*64.
// A either bf16 (Ab) or fp32 (Af, converted inline).  Output fp32 (Cf) or bf16 (Cb).
// mask_len: rows m with t >= mask_len[m] write 0 (Cf path only).
__global__ __launch_bounds__(256)
void mfma_nsplit(const float* __restrict__ Af, const bf16_t* __restrict__ Ab, int lda,
                 const bf16_t* __restrict__ W, int ldw,
                 const float* __restrict__ bias,
                 float* __restrict__ Cf, bf16_t* __restrict__ Cb, long ldc,
                 int N, int K, const int* __restrict__ mask_len, int t)
{
    const int lane = threadIdx.x & 63;
    const int wave = threadIdx.x >> 6;
    const int mr = lane & 15;
    const int quad = lane >> 4;
    const int m0 = blockIdx.x * 64;
    const int n0 = (blockIdx.y * (blockDim.x >> 6) + wave) * 64;

    const bf16_t* bp[4];
    #pragma unroll
    for (int nt = 0; nt < 4; nt++){
        int n = n0 + nt*16 + mr;
        if (n >= N) n = N - 1;
        bp[nt] = W + (size_t)n*ldw + quad*8;
    }

    f32x4 zero = {0.f, 0.f, 0.f, 0.f};
    f32x4 acc[4][4];
    #pragma unroll
    for (int i = 0; i < 4; i++)
        #pragma unroll
        for (int j = 0; j < 4; j++) acc[i][j] = zero;

    if (Ab){
        const bf16_t* ap[4];
        #pragma unroll
        for (int mt = 0; mt < 4; mt++)
            ap[mt] = Ab + (size_t)(m0 + mt*16 + mr)*lda + quad*8;
        for (int k = 0; k < K; k += 32){
            bf16x8 a[4], b[4];
            #pragma unroll
            for (int mt = 0; mt < 4; mt++) a[mt] = *(const bf16x8*)(ap[mt] + k);
            #pragma unroll
            for (int nt = 0; nt < 4; nt++) b[nt] = *(const bf16x8*)(bp[nt] + k);
            #pragma unroll
            for (int mt = 0; mt < 4; mt++)
                #pragma unroll
                for (int nt = 0; nt < 4; nt++)
                    acc[mt][nt] = __builtin_amdgcn_mfma_f32_16x16x32_bf16(a[mt], b[nt], acc[mt][nt], 0, 0, 0);
        }
    } else {
        const float* ap[4];
        #pragma unroll
        for (int mt = 0; mt < 4; mt++)
            ap[mt] = Af + (size_t)(m0 + mt*16 + mr)*lda + quad*8;
        for (int k = 0; k < K; k += 32){
            bf16x8 a[4], b[4];
            #pragma unroll
            for (int mt = 0; mt < 4; mt++){
                float4 u = *(const float4*)(ap[mt] + k);
                float4 v = *(const float4*)(ap[mt] + k + 4);
                bf16x8 tmp;
                tmp[0]=(__bf16)u.x; tmp[1]=(__bf16)u.y; tmp[2]=(__bf16)u.z; tmp[3]=(__bf16)u.w;
                tmp[4]=(__bf16)v.x; tmp[5]=(__bf16)v.y; tmp[6]=(__bf16)v.z; tmp[7]=(__bf16)v.w;
                a[mt] = tmp;
            }
            #pragma unroll
            for (int nt = 0; nt < 4; nt++) b[nt] = *(const bf16x8*)(bp[nt] + k);
            #pragma unroll
            for (int mt = 0; mt < 4; mt++)
                #pragma unroll
                for (int nt = 0; nt < 4; nt++)
                    acc[mt][nt] = __builtin_amdgcn_mfma_f32_16x16x32_bf16(a[mt], b[nt], acc[mt][nt], 0, 0, 0);
        }
    }

    // epilogue: C/D layout col = lane&15, row = quad*4 + r  [measured m89]
    if (Cb){
        #pragma unroll
        for (int mt = 0; mt < 4; mt++){
            #pragma unroll
            for (int nt = 0; nt < 4; nt++){
                int n = n0 + nt*16 + mr;
                if (n < N){
                    float bv = bias[n];
                    #pragma unroll
                    for (int r = 0; r < 4; r++){
                        int m = m0 + mt*16 + quad*4 + r;
                        Cb[(size_t)m*ldc + n] = __float2bfloat16(acc[mt][nt][r] + bv);
                    }
                }
            }
        }
    } else {
        #pragma unroll
        for (int mt = 0; mt < 4; mt++){
            #pragma unroll
            for (int r = 0; r < 4; r++){
                int m = m0 + mt*16 + quad*4 + r;
                bool msk = (mask_len != nullptr) && (t >= mask_len[m]);
                #pragma unroll
                for (int nt = 0; nt < 4; nt++){
                    int n = n0 + nt*16 + mr;
                    if (n < N){
                        float v = acc[mt][nt][r] + bias[n];
                        Cf[(size_t)m*ldc + n] = msk ? 0.f : v;
                    }
                }
            }
        }
    }
}

// ================= MFMA GEMM, waves split K, LDS reduce =================
// M = 64, N = gridDim.x*64 exact, K divisible by 128. 256 threads.
__global__ __launch_bounds__(256)
void mfma_ksplit(const bf16_t* __restrict__ A, int lda,
                 const bf16_t* __restrict__ W, int ldw,
                 const float* __restrict__ bias,
                 float* __restrict__ C, int ldc, int K)
{
    __shared__ float red[2][64][64];   // 32 KB
    const int lane = threadIdx.x & 63;
    const int wave = threadIdx.x >> 6;
    const int mr = lane & 15;
    const int quad = lane >> 4;
    const int n0 = blockIdx.x * 64;
    const int kw = K >> 2;
    const int kbeg = wave * kw;

    const bf16_t* ap[4];
    const bf16_t* bp[4];
    #pragma unroll
    for (int i = 0; i < 4; i++){
        ap[i] = A + (size_t)(i*16 + mr)*lda + quad*8;
        bp[i] = W + (size_t)(n0 + i*16 + mr)*ldw + quad*8;
    }

    f32x4 zero = {0.f, 0.f, 0.f, 0.f};
    f32x4 acc[4][4];
    #pragma unroll
    for (int i = 0; i < 4; i++)
        #pragma unroll
        for (int j = 0; j < 4; j++) acc[i][j] = zero;

    for (int k = kbeg; k < kbeg + kw; k += 32){
        bf16x8 a[4], b[4];
        #pragma unroll
        for (int mt = 0; mt < 4; mt++) a[mt] = *(const bf16x8*)(ap[mt] + k);
        #pragma unroll
        for (int nt = 0; nt < 4; nt++) b[nt] = *(const bf16x8*)(bp[nt] + k);
        #pragma unroll
        for (int mt = 0; mt < 4; mt++)
            #pragma unroll
            for (int nt = 0; nt < 4; nt++)
                acc[mt][nt] = __builtin_amdgcn_mfma_f32_16x16x32_bf16(a[mt], b[nt], acc[mt][nt], 0, 0, 0);
    }

    // tree-reduce the 4 per-wave partials in 32 KB of LDS
    if (wave >= 2){
        #pragma unroll
        for (int mt = 0; mt < 4; mt++)
            #pragma unroll
            for (int nt = 0; nt < 4; nt++)
                #pragma unroll
                for (int r = 0; r < 4; r++)
                    red[wave-2][mt*16 + quad*4 + r][nt*16 + mr] = acc[mt][nt][r];
    }
    __syncthreads();
    if (wave < 2){
        #pragma unroll
        for (int mt = 0; mt < 4; mt++)
            #pragma unroll
            for (int nt = 0; nt < 4; nt++)
                #pragma unroll
                for (int r = 0; r < 4; r++)
                    acc[mt][nt][r] += red[wave][mt*16 + quad*4 + r][nt*16 + mr];
    }
    __syncthreads();
    if (wave == 1){
        #pragma unroll
        for (int mt = 0; mt < 4; mt++)
            #pragma unroll
            for (int nt = 0; nt < 4; nt++)
                #pragma unroll
                for (int r = 0; r < 4; r++)
                    red[0][mt*16 + quad*4 + r][nt*16 + mr] = acc[mt][nt][r];
    }
    __syncthreads();
    if (wave == 0){
        #pragma unroll
        for (int mt = 0; mt < 4; mt++){
            #pragma unroll
            for (int nt = 0; nt < 4; nt++){
                int n = n0 + nt*16 + mr;
                float bv = bias[n];
                #pragma unroll
                for (int r = 0; r < 4; r++){
                    int m = mt*16 + quad*4 + r;
                    float v = acc[mt][nt][r] + red[0][m][nt*16 + mr] + bv;
                    C[(size_t)m*ldc + n] = v;
                }
            }
        }
    }
}

// ---------------- attention scores + softmax (one block per sorted b) ----------------
__global__ __launch_bounds__(256)
void attn_kernel(const bf16_t* __restrict__ att1,
                 const float* __restrict__ att2gate,  // [64][2560], cols 0..511 = att2
                 const float* __restrict__ faw, const float* __restrict__ fab,
                 const int* __restrict__ sort_ind,
                 const int* __restrict__ dec_len,
                 float* __restrict__ alpha_ws,
                 float* __restrict__ alphas_out, int t)
{
    __shared__ float a2s[Aq];
    __shared__ float fws[Aq];
    __shared__ float es[Pq];
    __shared__ float red[8];
    int b = blockIdx.x;
    int tid = threadIdx.x;
    for (int j = tid; j < Aq; j += 256){
        a2s[j] = att2gate[(size_t)b*2560 + j];
        fws[j] = faw[j];
    }
    __syncthreads();
    int src = sort_ind[b];
    const bf16_t* a1b = att1 + (size_t)src * Pq * Aq;
    int wid = tid >> 6, lane = tid & 63;
    float fb = fab[0];
    for (int p = wid; p < Pq; p += 4){
        const bf16_t* row = a1b + (size_t)p * Aq;
        float s = 0.f;
        #pragma unroll
        for (int i = 0; i < 8; i++){
            int a = lane + i*64;
            float v = __bfloat162float(row[a]) + a2s[a];
            v = v > 0.f ? v : 0.f;
            s += v * fws[a];
        }
        #pragma unroll
        for (int off = 32; off; off >>= 1) s += __shfl_xor(s, off);
        if (lane == 0) es[p] = s + fb;
    }
    __syncthreads();
    float v = (tid < Pq) ? es[tid] : -3.4e38f;
    float m = v;
    #pragma unroll
    for (int off = 32; off; off >>= 1) m = fmaxf(m, __shfl_xor(m, off));
    if ((tid & 63) == 0) red[tid >> 6] = m;
    __syncthreads();
    float bm = fmaxf(fmaxf(red[0], red[1]), fmaxf(red[2], red[3]));
    float ex = (tid < Pq) ? expf(v - bm) : 0.f;
    float s = ex;
    #pragma unroll
    for (int off = 32; off; off >>= 1) s += __shfl_xor(s, off);
    if ((tid & 63) == 0) red[4 + (tid >> 6)] = s;
    __syncthreads();
    float bs = red[4] + red[5] + red[6] + red[7];
    if (tid < Pq){
        float al = ex / bs;
        alpha_ws[b*Pq + tid] = al;
        float mask = (t < dec_len[b]) ? 1.f : 0.f;
        alphas_out[((size_t)b*Tq + t)*Pq + tid] = al * mask;
    }
}

// ---------------- awe = gate * (alpha @ enc), builds bf16 x_cat = [emb | awe | h] ----------------
__global__ __launch_bounds__(256)
void awe_xcat_kernel(const float* __restrict__ enc,
                     const float* __restrict__ att2gate,  // cols 512..2559 = gate pre-sigmoid
                     const float* __restrict__ alpha_ws,
                     const float* __restrict__ embed,
                     const float* __restrict__ hc,
                     const int* __restrict__ sort_ind,
                     const int* __restrict__ caps_sorted,
                     bf16_t* __restrict__ xcat, int t)
{
    int b = blockIdx.x, y = blockIdx.y, tid = threadIdx.x;
    __shared__ float als[Pq];
    if (tid < Pq) als[tid] = alpha_ws[b*Pq + tid];
    __syncthreads();
    int src = sort_ind[b];
    int d = y*256 + tid;
    const float* ebase = enc + (size_t)src * Pq * ENCq + d;
    float s = 0.f;
    for (int p = 0; p < Pq; p++) s += als[p] * ebase[(size_t)p*ENCq];
    float g = sigmoidf_(att2gate[(size_t)b*2560 + 512 + d]);
    xcat[(size_t)b*3072 + 512 + d] = __float2bfloat16(g * s);
    if (y == 0){
        int cap = caps_sorted[b*Lq + t];
        const float* er = embed + (size_t)cap*512;
        for (int j = tid; j < 512; j += 256) xcat[(size_t)b*3072 + j] = __float2bfloat16(er[j]);
    } else if (y == 1){
        for (int j = tid; j < Hq; j += 256) xcat[(size_t)b*3072 + 2560 + j] = __float2bfloat16(hc[b*1024 + j]);
    }
}

// ---------------- LSTM cell elementwise (updates hc fp32 and h bf16) ----------------
__global__ void lstm_kernel(const float* __restrict__ gates, float* __restrict__ hc,
                            bf16_t* __restrict__ hb)
{
    int idx = blockIdx.x*256 + threadIdx.x;
    if (idx >= Bq*Hq) return;
    int b = idx >> 9, j = idx & 511;
    const float* g = gates + (size_t)b*2048;
    float gi = sigmoidf_(g[j]);
    float gf = sigmoidf_(g[512 + j]);
    float gg = tanhf(g[1024 + j]);
    float go = sigmoidf_(g[1536 + j]);
    float c = hc[b*1024 + 512 + j];
    float cn = gf*c + gi*gg;
    float hn = go * tanhf(cn);
    hc[b*1024 + 512 + j] = cn;
    hc[b*1024 + j] = hn;
    hb[b*512 + j] = __float2bfloat16(hn);
}

extern "C" void kernel_launch(void* const* d_in, const int* in_sizes, int n_in,
                              void* d_out, int out_size, void* d_ws, size_t ws_size,
                              hipStream_t stream)
{
    const float* encoder_out = (const float*)d_in[0];
    const float* enc_att_w   = (const float*)d_in[1];
    const float* enc_att_b   = (const float*)d_in[2];
    const float* dec_att_w   = (const float*)d_in[3];
    const float* dec_att_b   = (const float*)d_in[4];
    const float* full_att_w  = (const float*)d_in[5];
    const float* full_att_b  = (const float*)d_in[6];
    const float* embed       = (const float*)d_in[7];
    const float* W_ih        = (const float*)d_in[8];
    const float* W_hh        = (const float*)d_in[9];
    const float* b_ih        = (const float*)d_in[10];
    const float* b_hh        = (const float*)d_in[11];
    const float* init_h_w    = (const float*)d_in[12];
    const float* init_h_b    = (const float*)d_in[13];
    const float* init_c_w    = (const float*)d_in[14];
    const float* init_c_b    = (const float*)d_in[15];
    const float* f_beta_w    = (const float*)d_in[16];
    const float* f_beta_b    = (const float*)d_in[17];
    const float* fc_w        = (const float*)d_in[18];
    const float* fc_b        = (const float*)d_in[19];
    const int*   enc_caps    = (const int*)d_in[20];
    const int*   cap_len     = (const int*)d_in[21];

    float* out_preds   = (float*)d_out;                       // 64*29*30000
    float* out_caps    = out_preds + (size_t)Bq*Tq*Vq;        // 64*30
    float* out_declen  = out_caps + Bq*Lq;                    // 64
    float* out_alphas  = out_declen + Bq;                     // 64*29*196
    float* out_sortind = out_alphas + (size_t)Bq*Tq*Pq;       // 64

    char* cur = (char*)d_ws;
    auto alloc = [&](size_t bytes) -> char* {
        char* p = cur;
        cur += (bytes + 255) & ~(size_t)255;
        return p;
    };
    bf16_t* att1_bf   = (bf16_t*)alloc((size_t)12544*512*2);
    bf16_t* fcw_bf    = (bf16_t*)alloc((size_t)30000*512*2);
    bf16_t* wcatg_bf  = (bf16_t*)alloc((size_t)2048*3072*2);
    bf16_t* whc_bf    = (bf16_t*)alloc((size_t)1024*2048*2);
    bf16_t* wcat2_bf  = (bf16_t*)alloc((size_t)2560*512*2);
    bf16_t* encattw_bf= (bf16_t*)alloc((size_t)512*2048*2);
    bf16_t* meanenc_bf= (bf16_t*)alloc((size_t)64*2048*2);
    bf16_t* h_bf      = (bf16_t*)alloc((size_t)64*512*2);
    bf16_t* xcat_bf   = (bf16_t*)alloc((size_t)64*3072*2);
    float* hc        = (float*)alloc((size_t)64*1024*4);
    float* att2gate  = (float*)alloc((size_t)64*2560*4);
    float* gatesb    = (float*)alloc((size_t)64*2048*4);
    float* bias_hc   = (float*)alloc(1024*4);
    float* bias2     = (float*)alloc(2560*4);
    float* bias_g    = (float*)alloc(2048*4);
    float* alpha_ws  = (float*)alloc((size_t)64*196*4);
    int* caps_sorted = (int*)alloc(Bq*Lq*4);
    int* sort_ind_i  = (int*)alloc(64*4);
    int* dec_len_i   = (int*)alloc(64*4);

    // ---- setup ----
    sort_kernel<<<1, 64, 0, stream>>>(cap_len, enc_caps, sort_ind_i, dec_len_i,
                                      caps_sorted, out_caps, out_declen, out_sortind);

    cvt_bf16<<<(1048576+255)/256, 256, 0, stream>>>(encattw_bf, enc_att_w, 1048576);
    cvt_bf16<<<(15360000+255)/256, 256, 0, stream>>>(fcw_bf, fc_w, 15360000);
    pack_rowcat_bf16<<<(2097152+255)/256, 256, 0, stream>>>(whc_bf, init_h_w, 1048576, init_c_w, 1048576);
    pack_rowcat_bf16<<<(1310720+255)/256, 256, 0, stream>>>(wcat2_bf, dec_att_w, 262144, f_beta_w, 1048576);
    pack_colcat_bf16<<<(6291456+255)/256, 256, 0, stream>>>(wcatg_bf, W_ih, W_hh);
    pack_rowcat_f32<<<(1024+255)/256, 256, 0, stream>>>(bias_hc, init_h_b, 512, init_c_b, 512);
    pack_rowcat_f32<<<(2560+255)/256, 256, 0, stream>>>(bias2, dec_att_b, 512, f_beta_b, 2048);
    biasg_kernel<<<8, 256, 0, stream>>>(bias_g, b_ih, b_hh);

    mean_enc_kernel<<<dim3(64,8), 256, 0, stream>>>(encoder_out, sort_ind_i, meanenc_bf);

    // h0/c0: M=64, N=1024, K=2048 (waves split K)
    mfma_ksplit<<<16, 256, 0, stream>>>(meanenc_bf, 2048, whc_bf, 2048, bias_hc, hc, 1024, 2048);
    h0_cvt<<<128, 256, 0, stream>>>(hc, h_bf);

    // att1: M=12544, N=512, K=2048, fp32 A inline-converted, bf16 C out
    mfma_nsplit<<<dim3(196,2), 256, 0, stream>>>(encoder_out, nullptr, 2048,
                                                 encattw_bf, 2048, enc_att_b,
                                                 nullptr, att1_bf, 512, 512, 2048, nullptr, 0);

    for (int t = 0; t < Tq; t++){
        // att2|gate: M=64, N=2560, K=512
        mfma_ksplit<<<40, 256, 0, stream>>>(h_bf, 512, wcat2_bf, 512, bias2, att2gate, 2560, 512);

        attn_kernel<<<64, 256, 0, stream>>>(att1_bf, att2gate, full_att_w, full_att_b,
                                            sort_ind_i, dec_len_i, alpha_ws, out_alphas, t);

        awe_xcat_kernel<<<dim3(64,8), 256, 0, stream>>>(encoder_out, att2gate, alpha_ws, embed,
                                                        hc, sort_ind_i, caps_sorted, xcat_bf, t);

        // gates: M=64, N=2048, K=3072
        mfma_ksplit<<<32, 256, 0, stream>>>(xcat_bf, 3072, wcatg_bf, 3072, bias_g, gatesb, 2048, 3072);

        lstm_kernel<<<128, 256, 0, stream>>>(gatesb, hc, h_bf);

        // preds: M=64, N=30000, K=512, masked epilogue (2 waves/block, 235 blocks)
        mfma_nsplit<<<dim3(1,235), 128, 0, stream>>>(nullptr, h_bf, 512,
                                                     fcw_bf, 512, fc_b,
                                                     out_preds + (size_t)t*Vq, nullptr, (long)Tq*Vq,
                                                     Vq, 512, dec_len_i, t);
    }
}

// Round 3
// 3271.962 us; speedup vs baseline: 1.7317x; 1.1172x over previous
//
#include <hip/hip_runtime.h>
#include <hip/hip_bf16.h>
#include <cstdint>

#define Bq 64
#define Pq 196
#define ENCq 2048
#define Aq 512
#define Hq 512
#define Vq 30000
#define Lq 30
#define Tq 29

typedef __bf16 bf16x8 __attribute__((ext_vector_type(8)));
typedef float f32x4 __attribute__((ext_vector_type(4)));
typedef __hip_bfloat16 bf16_t;

__device__ __forceinline__ float sigmoidf_(float x){ return 1.0f/(1.0f+expf(-x)); }

// ---------------- sort (stable descending argsort of lengths) ----------------
__global__ void sort_kernel(const int* __restrict__ cap_len, const int* __restrict__ caps,
                            int* __restrict__ sort_ind_i, int* __restrict__ dec_len_i,
                            int* __restrict__ caps_sorted,
                            float* __restrict__ out_caps, float* __restrict__ out_declen,
                            float* __restrict__ out_sortind)
{
    __shared__ int len[Bq];
    __shared__ int sidx[Bq];
    int i = threadIdx.x;
    len[i] = cap_len[i];
    __syncthreads();
    int li = len[i];
    int rank = 0;
    for (int j = 0; j < Bq; j++){
        int lj = len[j];
        rank += (lj > li) || (lj == li && j < i);
    }
    sidx[rank] = i;
    __syncthreads();
    int src = sidx[i];
    sort_ind_i[i] = src;
    int dl = len[src] - 1;
    dec_len_i[i] = dl;
    out_declen[i] = (float)dl;
    out_sortind[i] = (float)src;
    for (int tt = 0; tt < Lq; tt++){
        int cv = caps[src*Lq + tt];
        caps_sorted[i*Lq + tt] = cv;
        out_caps[i*Lq + tt] = (float)cv;
    }
}

// ---------------- pack / convert helpers ----------------
__global__ void cvt_bf16(bf16_t* __restrict__ dst, const float* __restrict__ src, int n)
{
    int i = blockIdx.x*256 + threadIdx.x;
    if (i < n) dst[i] = __float2bfloat16(src[i]);
}

__global__ void pack_rowcat_bf16(bf16_t* __restrict__ dst, const float* __restrict__ a, int na,
                                 const float* __restrict__ b, int nb)
{
    int i = blockIdx.x*256 + threadIdx.x;
    if (i < na) dst[i] = __float2bfloat16(a[i]);
    else if (i < na + nb) dst[i] = __float2bfloat16(b[i - na]);
}

__global__ void pack_rowcat_f32(float* __restrict__ dst, const float* __restrict__ a, int na,
                                const float* __restrict__ b, int nb)
{
    int i = blockIdx.x*256 + threadIdx.x;
    if (i < na) dst[i] = a[i];
    else if (i < na + nb) dst[i] = b[i - na];
}

// wcatg with row permutation: dst row r' = 4*j + g holds source row g*512+j of [W_ih|W_hh]
__global__ void pack_colcat_perm_bf16(bf16_t* __restrict__ dst, const float* __restrict__ a,
                                      const float* __restrict__ b)
{
    int i = blockIdx.x*256 + threadIdx.x;
    if (i >= 2048*3072) return;
    int rp = i / 3072, c = i % 3072;
    int g = rp & 3, j = rp >> 2;
    int r = g*512 + j;
    float v = (c < 2560) ? a[(size_t)r*2560 + c] : b[(size_t)r*512 + (c - 2560)];
    dst[i] = __float2bfloat16(v);
}

__global__ void biasg_perm_kernel(float* __restrict__ dst, const float* __restrict__ bi,
                                  const float* __restrict__ bh)
{
    int i = blockIdx.x*256 + threadIdx.x;
    if (i >= 2048) return;
    int g = i & 3, j = i >> 2;
    int r = g*512 + j;
    dst[i] = bi[r] + bh[r];
}

// ---------------- gather encoder into sorted order, convert to bf16, compute mean ----------------
__global__ __launch_bounds__(256)
void gather_cvt_mean(const float* __restrict__ enc, const int* __restrict__ sort_ind,
                     bf16_t* __restrict__ enc_bf, bf16_t* __restrict__ mean_bf)
{
    int b = blockIdx.x;
    int d = blockIdx.y*256 + threadIdx.x;
    int src = sort_ind[b];
    const float* col = enc + (size_t)src * Pq * ENCq + d;
    bf16_t* dst = enc_bf + (size_t)b * Pq * ENCq + d;
    float s = 0.f;
    for (int p = 0; p < Pq; p++){
        float v = col[(size_t)p*ENCq];
        s += v;
        dst[(size_t)p*ENCq] = __float2bfloat16(v);
    }
    mean_bf[(size_t)b*ENCq + d] = __float2bfloat16(s * (1.0f/196.0f));
}

// ================= att1 GEMM (bf16 A, bf16 out) =================
// C[m,n] = sum_k A[m,k]*W[n,k] + bias[n]; grid (M/64, 2), 256 thr (4 waves split N over 512)
__global__ __launch_bounds__(256)
void att1_gemm(const bf16_t* __restrict__ A, const bf16_t* __restrict__ W,
               const float* __restrict__ bias, bf16_t* __restrict__ C)
{
    const int lane = threadIdx.x & 63;
    const int wave = threadIdx.x >> 6;
    const int mr = lane & 15;
    const int quad = lane >> 4;
    const int m0 = blockIdx.x * 64;
    const int n0 = (blockIdx.y * 4 + wave) * 64;

    const bf16_t* ap[4];
    const bf16_t* bp[4];
    #pragma unroll
    for (int i = 0; i < 4; i++){
        ap[i] = A + (size_t)(m0 + i*16 + mr)*ENCq + quad*8;
        bp[i] = W + (size_t)(n0 + i*16 + mr)*ENCq + quad*8;
    }
    f32x4 zero = {0.f,0.f,0.f,0.f};
    f32x4 acc[4][4];
    #pragma unroll
    for (int i = 0; i < 4; i++)
        #pragma unroll
        for (int j = 0; j < 4; j++) acc[i][j] = zero;

    for (int k = 0; k < ENCq; k += 32){
        bf16x8 a[4], b[4];
        #pragma unroll
        for (int mt = 0; mt < 4; mt++) a[mt] = *(const bf16x8*)(ap[mt] + k);
        #pragma unroll
        for (int nt = 0; nt < 4; nt++) b[nt] = *(const bf16x8*)(bp[nt] + k);
        #pragma unroll
        for (int mt = 0; mt < 4; mt++)
            #pragma unroll
            for (int nt = 0; nt < 4; nt++)
                acc[mt][nt] = __builtin_amdgcn_mfma_f32_16x16x32_bf16(a[mt], b[nt], acc[mt][nt], 0, 0, 0);
    }
    #pragma unroll
    for (int mt = 0; mt < 4; mt++){
        #pragma unroll
        for (int nt = 0; nt < 4; nt++){
            int n = n0 + nt*16 + mr;
            float bv = bias[n];
            #pragma unroll
            for (int r = 0; r < 4; r++){
                int m = m0 + mt*16 + quad*4 + r;
                C[(size_t)m*Aq + n] = __float2bfloat16(acc[mt][nt][r] + bv);
            }
        }
    }
}

// ================= MFMA GEMM, waves split K, LDS reduce =================
// M = 64, N = gridDim.x*64, K divisible by 128. 256 threads.
// hb: optional bf16 mirror of C columns [0,512)
__global__ __launch_bounds__(256)
void mfma_ksplit(const bf16_t* __restrict__ A, int lda,
                 const bf16_t* __restrict__ W, int ldw,
                 const float* __restrict__ bias,
                 float* __restrict__ C, int ldc, int K, bf16_t* __restrict__ hb)
{
    __shared__ float red[2][64][64];
    const int lane = threadIdx.x & 63;
    const int wave = threadIdx.x >> 6;
    const int mr = lane & 15;
    const int quad = lane >> 4;
    const int n0 = blockIdx.x * 64;
    const int kw = K >> 2;
    const int kbeg = wave * kw;

    const bf16_t* ap[4];
    const bf16_t* bp[4];
    #pragma unroll
    for (int i = 0; i < 4; i++){
        ap[i] = A + (size_t)(i*16 + mr)*lda + quad*8;
        bp[i] = W + (size_t)(n0 + i*16 + mr)*ldw + quad*8;
    }
    f32x4 zero = {0.f,0.f,0.f,0.f};
    f32x4 acc[4][4];
    #pragma unroll
    for (int i = 0; i < 4; i++)
        #pragma unroll
        for (int j = 0; j < 4; j++) acc[i][j] = zero;

    for (int k = kbeg; k < kbeg + kw; k += 32){
        bf16x8 a[4], b[4];
        #pragma unroll
        for (int mt = 0; mt < 4; mt++) a[mt] = *(const bf16x8*)(ap[mt] + k);
        #pragma unroll
        for (int nt = 0; nt < 4; nt++) b[nt] = *(const bf16x8*)(bp[nt] + k);
        #pragma unroll
        for (int mt = 0; mt < 4; mt++)
            #pragma unroll
            for (int nt = 0; nt < 4; nt++)
                acc[mt][nt] = __builtin_amdgcn_mfma_f32_16x16x32_bf16(a[mt], b[nt], acc[mt][nt], 0, 0, 0);
    }

    if (wave >= 2){
        #pragma unroll
        for (int mt = 0; mt < 4; mt++)
            #pragma unroll
            for (int nt = 0; nt < 4; nt++)
                #pragma unroll
                for (int r = 0; r < 4; r++)
                    red[wave-2][mt*16 + quad*4 + r][nt*16 + mr] = acc[mt][nt][r];
    }
    __syncthreads();
    if (wave < 2){
        #pragma unroll
        for (int mt = 0; mt < 4; mt++)
            #pragma unroll
            for (int nt = 0; nt < 4; nt++)
                #pragma unroll
                for (int r = 0; r < 4; r++)
                    acc[mt][nt][r] += red[wave][mt*16 + quad*4 + r][nt*16 + mr];
    }
    __syncthreads();
    if (wave == 1){
        #pragma unroll
        for (int mt = 0; mt < 4; mt++)
            #pragma unroll
            for (int nt = 0; nt < 4; nt++)
                #pragma unroll
                for (int r = 0; r < 4; r++)
                    red[0][mt*16 + quad*4 + r][nt*16 + mr] = acc[mt][nt][r];
    }
    __syncthreads();
    if (wave == 0){
        #pragma unroll
        for (int mt = 0; mt < 4; mt++){
            #pragma unroll
            for (int nt = 0; nt < 4; nt++){
                int n = n0 + nt*16 + mr;
                float bv = bias[n];
                #pragma unroll
                for (int r = 0; r < 4; r++){
                    int m = mt*16 + quad*4 + r;
                    float v = acc[mt][nt][r] + red[0][m][nt*16 + mr] + bv;
                    C[(size_t)m*ldc + n] = v;
                    if (hb && n < Hq) hb[(size_t)m*Hq + n] = __float2bfloat16(v);
                }
            }
        }
    }
}

// ================= gates GEMM (K=3072) fused with LSTM =================
// W rows permuted: r' = 4*j + g. grid 32 blocks, 256 thr.
__global__ __launch_bounds__(256)
void gates_lstm(const bf16_t* __restrict__ A, const bf16_t* __restrict__ W,
                const float* __restrict__ bias, float* __restrict__ hc,
                bf16_t* __restrict__ hb)
{
    __shared__ float red[2][64][64];
    const int lane = threadIdx.x & 63;
    const int wave = threadIdx.x >> 6;
    const int mr = lane & 15;
    const int quad = lane >> 4;
    const int n0 = blockIdx.x * 64;
    const int kw = 3072 >> 2;
    const int kbeg = wave * kw;

    const bf16_t* ap[4];
    const bf16_t* bp[4];
    #pragma unroll
    for (int i = 0; i < 4; i++){
        ap[i] = A + (size_t)(i*16 + mr)*3072 + quad*8;
        bp[i] = W + (size_t)(n0 + i*16 + mr)*3072 + quad*8;
    }
    f32x4 zero = {0.f,0.f,0.f,0.f};
    f32x4 acc[4][4];
    #pragma unroll
    for (int i = 0; i < 4; i++)
        #pragma unroll
        for (int j = 0; j < 4; j++) acc[i][j] = zero;

    for (int k = kbeg; k < kbeg + kw; k += 32){
        bf16x8 a[4], b[4];
        #pragma unroll
        for (int mt = 0; mt < 4; mt++) a[mt] = *(const bf16x8*)(ap[mt] + k);
        #pragma unroll
        for (int nt = 0; nt < 4; nt++) b[nt] = *(const bf16x8*)(bp[nt] + k);
        #pragma unroll
        for (int mt = 0; mt < 4; mt++)
            #pragma unroll
            for (int nt = 0; nt < 4; nt++)
                acc[mt][nt] = __builtin_amdgcn_mfma_f32_16x16x32_bf16(a[mt], b[nt], acc[mt][nt], 0, 0, 0);
    }

    if (wave >= 2){
        #pragma unroll
        for (int mt = 0; mt < 4; mt++)
            #pragma unroll
            for (int nt = 0; nt < 4; nt++)
                #pragma unroll
                for (int r = 0; r < 4; r++)
                    red[wave-2][mt*16 + quad*4 + r][nt*16 + mr] = acc[mt][nt][r];
    }
    __syncthreads();
    if (wave < 2){
        #pragma unroll
        for (int mt = 0; mt < 4; mt++)
            #pragma unroll
            for (int nt = 0; nt < 4; nt++)
                #pragma unroll
                for (int r = 0; r < 4; r++)
                    acc[mt][nt][r] += red[wave][mt*16 + quad*4 + r][nt*16 + mr];
    }
    __syncthreads();
    if (wave == 1){
        #pragma unroll
        for (int mt = 0; mt < 4; mt++)
            #pragma unroll
            for (int nt = 0; nt < 4; nt++)
                #pragma unroll
                for (int r = 0; r < 4; r++)
                    red[0][mt*16 + quad*4 + r][nt*16 + mr] = acc[mt][nt][r];
    }
    __syncthreads();
    if (wave == 0){
        #pragma unroll
        for (int mt = 0; mt < 4; mt++){
            #pragma unroll
            for (int nt = 0; nt < 4; nt++){
                int nl = nt*16 + mr;
                float bv = bias[n0 + nl];
                #pragma unroll
                for (int r = 0; r < 4; r++){
                    int m = mt*16 + quad*4 + r;
                    float v = acc[mt][nt][r] + red[0][m][nl] + bv;
                    red[0][m][nl] = v;   // same lane read+write: safe
                }
            }
        }
    }
    __syncthreads();
    // LSTM elementwise on the block's 16 hidden units x 64 batch
    #pragma unroll
    for (int q = 0; q < 4; q++){
        int idx = threadIdx.x + 256*q;
        int m = idx & 63;
        int jl = idx >> 6;
        int j = (n0 >> 2) + jl;
        float gi = sigmoidf_(red[0][m][4*jl + 0]);
        float gf = sigmoidf_(red[0][m][4*jl + 1]);
        float gg = tanhf(red[0][m][4*jl + 2]);
        float go = sigmoidf_(red[0][m][4*jl + 3]);
        float c  = hc[m*1024 + 512 + j];
        float cn = gf*c + gi*gg;
        float hn = go * tanhf(cn);
        hc[m*1024 + 512 + j] = cn;
        hc[m*1024 + j] = hn;
        hb[m*512 + j] = __float2bfloat16(hn);
    }
}

// ================= preds GEMM: h (LDS-staged) x fc_w, masked epilogue =================
// grid 469 blocks x 256 thr; wave-tile = 64 rows x 16 cols; K=512 unrolled.
__global__ __launch_bounds__(256)
void preds_gemm(const bf16_t* __restrict__ hbf, const bf16_t* __restrict__ W,
                const float* __restrict__ bias, float* __restrict__ C,
                const int* __restrict__ mask_len, int t)
{
    __shared__ __bf16 hs[64][520];   // +8 pad: LDS row stride 1040B -> bank stride 4
    {
        int r = threadIdx.x >> 2;
        int c0 = (threadIdx.x & 3) * 128;
        const bf16_t* src = hbf + (size_t)r*512 + c0;
        #pragma unroll
        for (int i = 0; i < 16; i++)
            *(bf16x8*)&hs[r][c0 + i*8] = *(const bf16x8*)(src + i*8);
    }
    __syncthreads();

    const int lane = threadIdx.x & 63;
    const int wave = threadIdx.x >> 6;
    const int mr = lane & 15;
    const int quad = lane >> 4;
    const int n0 = (blockIdx.x * 4 + wave) * 16;
    if (n0 >= Vq) return;

    const bf16_t* bp = W + (size_t)(n0 + mr)*512 + quad*8;
    f32x4 zero = {0.f,0.f,0.f,0.f};
    f32x4 acc[4] = {zero, zero, zero, zero};

    #pragma unroll
    for (int kk = 0; kk < 16; kk++){
        bf16x8 b = *(const bf16x8*)(bp + kk*32);
        bf16x8 a[4];
        #pragma unroll
        for (int mt = 0; mt < 4; mt++)
            a[mt] = *(const bf16x8*)&hs[mt*16 + mr][kk*32 + quad*8];
        #pragma unroll
        for (int mt = 0; mt < 4; mt++)
            acc[mt] = __builtin_amdgcn_mfma_f32_16x16x32_bf16(a[mt], b, acc[mt], 0, 0, 0);
    }

    float bv = bias[n0 + mr];
    #pragma unroll
    for (int mt = 0; mt < 4; mt++){
        #pragma unroll
        for (int r = 0; r < 4; r++){
            int m = mt*16 + quad*4 + r;
            bool msk = (t >= mask_len[m]);
            float v = acc[mt][r] + bv;
            C[(size_t)m*(Tq*Vq) + n0 + mr] = msk ? 0.f : v;
        }
    }
}

// ---------------- attention scores + softmax (one block per sorted b) ----------------
__global__ __launch_bounds__(256)
void attn_kernel(const bf16_t* __restrict__ att1,      // sorted order
                 const float* __restrict__ att2gate,   // [64][2560], cols 0..511 = att2
                 const float* __restrict__ faw, const float* __restrict__ fab,
                 const int* __restrict__ dec_len,
                 float* __restrict__ alpha_ws,
                 float* __restrict__ alphas_out, int t)
{
    __shared__ float es[Pq];
    __shared__ float red[8];
    int b = blockIdx.x;
    int tid = threadIdx.x;
    int wid = tid >> 6, lane = tid & 63;

    // att2 + full_att_w fragments in registers: lane owns elements lane*8..lane*8+7
    float a2r[8], fwr[8];
    {
        const float4* a2p = (const float4*)(att2gate + (size_t)b*2560);
        const float4* fwp = (const float4*)faw;
        float4 u0 = a2p[lane*2], u1 = a2p[lane*2+1];
        float4 w0 = fwp[lane*2], w1 = fwp[lane*2+1];
        a2r[0]=u0.x; a2r[1]=u0.y; a2r[2]=u0.z; a2r[3]=u0.w;
        a2r[4]=u1.x; a2r[5]=u1.y; a2r[6]=u1.z; a2r[7]=u1.w;
        fwr[0]=w0.x; fwr[1]=w0.y; fwr[2]=w0.z; fwr[3]=w0.w;
        fwr[4]=w1.x; fwr[5]=w1.y; fwr[6]=w1.z; fwr[7]=w1.w;
    }
    float fb = fab[0];
    const bf16_t* a1b = att1 + (size_t)b * Pq * Aq + lane*8;
    for (int p = wid; p < Pq; p += 4){
        bf16x8 rv = *(const bf16x8*)(a1b + (size_t)p * Aq);
        float s = 0.f;
        #pragma unroll
        for (int i = 0; i < 8; i++){
            float v = (float)rv[i] + a2r[i];
            v = v > 0.f ? v : 0.f;
            s += v * fwr[i];
        }
        #pragma unroll
        for (int off = 32; off; off >>= 1) s += __shfl_xor(s, off);
        if (lane == 0) es[p] = s + fb;
    }
    __syncthreads();
    float v = (tid < Pq) ? es[tid] : -3.4e38f;
    float m = v;
    #pragma unroll
    for (int off = 32; off; off >>= 1) m = fmaxf(m, __shfl_xor(m, off));
    if ((tid & 63) == 0) red[tid >> 6] = m;
    __syncthreads();
    float bm = fmaxf(fmaxf(red[0], red[1]), fmaxf(red[2], red[3]));
    float ex = (tid < Pq) ? expf(v - bm) : 0.f;
    float s = ex;
    #pragma unroll
    for (int off = 32; off; off >>= 1) s += __shfl_xor(s, off);
    if ((tid & 63) == 0) red[4 + (tid >> 6)] = s;
    __syncthreads();
    float bs = red[4] + red[5] + red[6] + red[7];
    if (tid < Pq){
        float al = ex / bs;
        alpha_ws[b*Pq + tid] = al;
        float mask = (t < dec_len[b]) ? 1.f : 0.f;
        alphas_out[((size_t)b*Tq + t)*Pq + tid] = al * mask;
    }
}

// ---------------- awe = gate * (alpha @ enc_bf), builds bf16 x_cat = [emb | awe | h] ----------------
__global__ __launch_bounds__(256)
void awe_xcat_kernel(const bf16_t* __restrict__ enc_bf,   // sorted
                     const float* __restrict__ att2gate,
                     const float* __restrict__ alpha_ws,
                     const float* __restrict__ embed,
                     const float* __restrict__ hc,
                     const int* __restrict__ caps_sorted,
                     bf16_t* __restrict__ xcat, int t)
{
    int b = blockIdx.x, y = blockIdx.y, tid = threadIdx.x;
    __shared__ float als[Pq];
    if (tid < Pq) als[tid] = alpha_ws[b*Pq + tid];
    __syncthreads();
    int d = y*256 + tid;
    const bf16_t* ebase = enc_bf + (size_t)b * Pq * ENCq + d;
    float s = 0.f;
    for (int p = 0; p < Pq; p++) s += als[p] * (float)ebase[(size_t)p*ENCq];
    float g = sigmoidf_(att2gate[(size_t)b*2560 + 512 + d]);
    xcat[(size_t)b*3072 + 512 + d] = __float2bfloat16(g * s);
    if (y == 0){
        int cap = caps_sorted[b*Lq + t];
        const float* er = embed + (size_t)cap*512;
        for (int j = tid; j < 512; j += 256) xcat[(size_t)b*3072 + j] = __float2bfloat16(er[j]);
    } else if (y == 1){
        for (int j = tid; j < Hq; j += 256) xcat[(size_t)b*3072 + 2560 + j] = __float2bfloat16(hc[b*1024 + j]);
    }
}

extern "C" void kernel_launch(void* const* d_in, const int* in_sizes, int n_in,
                              void* d_out, int out_size, void* d_ws, size_t ws_size,
                              hipStream_t stream)
{
    const float* encoder_out = (const float*)d_in[0];
    const float* enc_att_w   = (const float*)d_in[1];
    const float* enc_att_b   = (const float*)d_in[2];
    const float* dec_att_w   = (const float*)d_in[3];
    const float* dec_att_b   = (const float*)d_in[4];
    const float* full_att_w  = (const float*)d_in[5];
    const float* full_att_b  = (const float*)d_in[6];
    const float* embed       = (const float*)d_in[7];
    const float* W_ih        = (const float*)d_in[8];
    const float* W_hh        = (const float*)d_in[9];
    const float* b_ih        = (const float*)d_in[10];
    const float* b_hh        = (const float*)d_in[11];
    const float* init_h_w    = (const float*)d_in[12];
    const float* init_h_b    = (const float*)d_in[13];
    const float* init_c_w    = (const float*)d_in[14];
    const float* init_c_b    = (const float*)d_in[15];
    const float* f_beta_w    = (const float*)d_in[16];
    const float* f_beta_b    = (const float*)d_in[17];
    const float* fc_w        = (const float*)d_in[18];
    const float* fc_b        = (const float*)d_in[19];
    const int*   enc_caps    = (const int*)d_in[20];
    const int*   cap_len     = (const int*)d_in[21];

    float* out_preds   = (float*)d_out;
    float* out_caps    = out_preds + (size_t)Bq*Tq*Vq;
    float* out_declen  = out_caps + Bq*Lq;
    float* out_alphas  = out_declen + Bq;
    float* out_sortind = out_alphas + (size_t)Bq*Tq*Pq;

    char* cur = (char*)d_ws;
    auto alloc = [&](size_t bytes) -> char* {
        char* p = cur;
        cur += (bytes + 255) & ~(size_t)255;
        return p;
    };
    bf16_t* enc_bf    = (bf16_t*)alloc((size_t)12544*2048*2);
    bf16_t* att1_bf   = (bf16_t*)alloc((size_t)12544*512*2);
    bf16_t* fcw_bf    = (bf16_t*)alloc((size_t)30000*512*2);
    bf16_t* wcatg_bf  = (bf16_t*)alloc((size_t)2048*3072*2);
    bf16_t* whc_bf    = (bf16_t*)alloc((size_t)1024*2048*2);
    bf16_t* wcat2_bf  = (bf16_t*)alloc((size_t)2560*512*2);
    bf16_t* encattw_bf= (bf16_t*)alloc((size_t)512*2048*2);
    bf16_t* meanenc_bf= (bf16_t*)alloc((size_t)64*2048*2);
    bf16_t* h_bf      = (bf16_t*)alloc((size_t)64*512*2);
    bf16_t* xcat_bf   = (bf16_t*)alloc((size_t)64*3072*2);
    float* hc        = (float*)alloc((size_t)64*1024*4);
    float* att2gate  = (float*)alloc((size_t)64*2560*4);
    float* bias_hc   = (float*)alloc(1024*4);
    float* bias2     = (float*)alloc(2560*4);
    float* bias_g    = (float*)alloc(2048*4);
    float* alpha_ws  = (float*)alloc((size_t)64*196*4);
    int* caps_sorted = (int*)alloc(Bq*Lq*4);
    int* sort_ind_i  = (int*)alloc(64*4);
    int* dec_len_i   = (int*)alloc(64*4);

    // ---- setup ----
    sort_kernel<<<1, 64, 0, stream>>>(cap_len, enc_caps, sort_ind_i, dec_len_i,
                                      caps_sorted, out_caps, out_declen, out_sortind);

    cvt_bf16<<<(1048576+255)/256, 256, 0, stream>>>(encattw_bf, enc_att_w, 1048576);
    cvt_bf16<<<(15360000+255)/256, 256, 0, stream>>>(fcw_bf, fc_w, 15360000);
    pack_rowcat_bf16<<<(2097152+255)/256, 256, 0, stream>>>(whc_bf, init_h_w, 1048576, init_c_w, 1048576);
    pack_rowcat_bf16<<<(1310720+255)/256, 256, 0, stream>>>(wcat2_bf, dec_att_w, 262144, f_beta_w, 1048576);
    pack_colcat_perm_bf16<<<(6291456+255)/256, 256, 0, stream>>>(wcatg_bf, W_ih, W_hh);
    pack_rowcat_f32<<<(1024+255)/256, 256, 0, stream>>>(bias_hc, init_h_b, 512, init_c_b, 512);
    pack_rowcat_f32<<<(2560+255)/256, 256, 0, stream>>>(bias2, dec_att_b, 512, f_beta_b, 2048);
    biasg_perm_kernel<<<8, 256, 0, stream>>>(bias_g, b_ih, b_hh);

    gather_cvt_mean<<<dim3(64,8), 256, 0, stream>>>(encoder_out, sort_ind_i, enc_bf, meanenc_bf);

    // h0/c0: M=64, N=1024, K=2048 (waves split K); writes h_bf for cols<512
    mfma_ksplit<<<16, 256, 0, stream>>>(meanenc_bf, 2048, whc_bf, 2048, bias_hc, hc, 1024, 2048, h_bf);

    // att1: M=12544 (sorted), N=512, K=2048, bf16 in/out
    att1_gemm<<<dim3(196,2), 256, 0, stream>>>(enc_bf, encattw_bf, enc_att_b, att1_bf);

    for (int t = 0; t < Tq; t++){
        // att2|gate: M=64, N=2560, K=512
        mfma_ksplit<<<40, 256, 0, stream>>>(h_bf, 512, wcat2_bf, 512, bias2, att2gate, 2560, 512, nullptr);

        attn_kernel<<<64, 256, 0, stream>>>(att1_bf, att2gate, full_att_w, full_att_b,
                                            dec_len_i, alpha_ws, out_alphas, t);

        awe_xcat_kernel<<<dim3(64,8), 256, 0, stream>>>(enc_bf, att2gate, alpha_ws, embed,
                                                        hc, caps_sorted, xcat_bf, t);

        // gates GEMM + LSTM fused (permuted wcatg)
        gates_lstm<<<32, 256, 0, stream>>>(xcat_bf, wcatg_bf, bias_g, hc, h_bf);

        // preds: M=64, N=30000, K=512, LDS-staged h, masked epilogue
        preds_gemm<<<469, 256, 0, stream>>>(h_bf, fcw_bf, fc_b,
                                            out_preds + (size_t)t*Vq, dec_len_i, t);
    }
}

// Round 4
// 3115.254 us; speedup vs baseline: 1.8188x; 1.0503x over previous
//
#include <hip/hip_runtime.h>
#include <hip/hip_bf16.h>
#include <cstdint>

#define Bq 64
#define Pq 196
#define ENCq 2048
#define Aq 512
#define Hq 512
#define Vq 30000
#define Lq 30
#define Tq 29

typedef __bf16 bf16x8 __attribute__((ext_vector_type(8)));
typedef float f32x4 __attribute__((ext_vector_type(4)));
typedef __hip_bfloat16 bf16_t;

__device__ __forceinline__ float sigmoidf_(float x){ return 1.0f/(1.0f+expf(-x)); }

// ---------------- sort (stable descending argsort of lengths) ----------------
__global__ void sort_kernel(const int* __restrict__ cap_len, const int* __restrict__ caps,
                            int* __restrict__ sort_ind_i, int* __restrict__ dec_len_i,
                            int* __restrict__ caps_sorted,
                            float* __restrict__ out_caps, float* __restrict__ out_declen,
                            float* __restrict__ out_sortind)
{
    __shared__ int len[Bq];
    __shared__ int sidx[Bq];
    int i = threadIdx.x;
    len[i] = cap_len[i];
    __syncthreads();
    int li = len[i];
    int rank = 0;
    for (int j = 0; j < Bq; j++){
        int lj = len[j];
        rank += (lj > li) || (lj == li && j < i);
    }
    sidx[rank] = i;
    __syncthreads();
    int src = sidx[i];
    sort_ind_i[i] = src;
    int dl = len[src] - 1;
    dec_len_i[i] = dl;
    out_declen[i] = (float)dl;
    out_sortind[i] = (float)src;
    for (int tt = 0; tt < Lq; tt++){
        int cv = caps[src*Lq + tt];
        caps_sorted[i*Lq + tt] = cv;
        out_caps[i*Lq + tt] = (float)cv;
    }
}

// ---------------- pack / convert helpers ----------------
__global__ void cvt_bf16(bf16_t* __restrict__ dst, const float* __restrict__ src, int n)
{
    int i = blockIdx.x*256 + threadIdx.x;
    if (i < n) dst[i] = __float2bfloat16(src[i]);
}

__global__ void pack_rowcat_bf16(bf16_t* __restrict__ dst, const float* __restrict__ a, int na,
                                 const float* __restrict__ b, int nb)
{
    int i = blockIdx.x*256 + threadIdx.x;
    if (i < na) dst[i] = __float2bfloat16(a[i]);
    else if (i < na + nb) dst[i] = __float2bfloat16(b[i - na]);
}

__global__ void pack_rowcat_f32(float* __restrict__ dst, const float* __restrict__ a, int na,
                                const float* __restrict__ b, int nb)
{
    int i = blockIdx.x*256 + threadIdx.x;
    if (i < na) dst[i] = a[i];
    else if (i < na + nb) dst[i] = b[i - na];
}

// wcatg with row permutation: dst row r' = 4*j + g holds source row g*512+j of [W_ih|W_hh]
__global__ void pack_colcat_perm_bf16(bf16_t* __restrict__ dst, const float* __restrict__ a,
                                      const float* __restrict__ b)
{
    int i = blockIdx.x*256 + threadIdx.x;
    if (i >= 2048*3072) return;
    int rp = i / 3072, c = i % 3072;
    int g = rp & 3, j = rp >> 2;
    int r = g*512 + j;
    float v = (c < 2560) ? a[(size_t)r*2560 + c] : b[(size_t)r*512 + (c - 2560)];
    dst[i] = __float2bfloat16(v);
}

__global__ void biasg_perm_kernel(float* __restrict__ dst, const float* __restrict__ bi,
                                  const float* __restrict__ bh)
{
    int i = blockIdx.x*256 + threadIdx.x;
    if (i >= 2048) return;
    int g = i & 3, j = i >> 2;
    int r = g*512 + j;
    dst[i] = bi[r] + bh[r];
}

// ---------------- gather encoder into sorted order, convert to bf16, compute mean ----------------
__global__ __launch_bounds__(256)
void gather_cvt_mean(const float* __restrict__ enc, const int* __restrict__ sort_ind,
                     bf16_t* __restrict__ enc_bf, bf16_t* __restrict__ mean_bf)
{
    int b = blockIdx.x;
    int d = blockIdx.y*256 + threadIdx.x;
    int src = sort_ind[b];
    const float* col = enc + (size_t)src * Pq * ENCq + d;
    bf16_t* dst = enc_bf + (size_t)b * Pq * ENCq + d;
    float s = 0.f;
    for (int p = 0; p < Pq; p++){
        float v = col[(size_t)p*ENCq];
        s += v;
        dst[(size_t)p*ENCq] = __float2bfloat16(v);
    }
    mean_bf[(size_t)b*ENCq + d] = __float2bfloat16(s * (1.0f/196.0f));
}

// ================= h0/c0 GEMM: waves split K, LDS reduce =================
// M=64, N=1024 (16 blocks), K=2048. n<512 -> h0 (bf16), n>=512 -> c0 (fp32).
__global__ __launch_bounds__(256)
void hc0_ksplit(const bf16_t* __restrict__ A, const bf16_t* __restrict__ W,
                const float* __restrict__ bias,
                bf16_t* __restrict__ h0, float* __restrict__ c_state)
{
    __shared__ float red[2][64][64];
    const int lane = threadIdx.x & 63;
    const int wave = threadIdx.x >> 6;
    const int mr = lane & 15;
    const int quad = lane >> 4;
    const int n0 = blockIdx.x * 64;
    const int kw = 2048 >> 2;
    const int kbeg = wave * kw;

    const bf16_t* ap[4];
    const bf16_t* bp[4];
    #pragma unroll
    for (int i = 0; i < 4; i++){
        ap[i] = A + (size_t)(i*16 + mr)*2048 + quad*8;
        bp[i] = W + (size_t)(n0 + i*16 + mr)*2048 + quad*8;
    }
    f32x4 zero = {0.f,0.f,0.f,0.f};
    f32x4 acc[4][4];
    #pragma unroll
    for (int i = 0; i < 4; i++)
        #pragma unroll
        for (int j = 0; j < 4; j++) acc[i][j] = zero;

    for (int k = kbeg; k < kbeg + kw; k += 32){
        bf16x8 a[4], b[4];
        #pragma unroll
        for (int mt = 0; mt < 4; mt++) a[mt] = *(const bf16x8*)(ap[mt] + k);
        #pragma unroll
        for (int nt = 0; nt < 4; nt++) b[nt] = *(const bf16x8*)(bp[nt] + k);
        #pragma unroll
        for (int mt = 0; mt < 4; mt++)
            #pragma unroll
            for (int nt = 0; nt < 4; nt++)
                acc[mt][nt] = __builtin_amdgcn_mfma_f32_16x16x32_bf16(a[mt], b[nt], acc[mt][nt], 0, 0, 0);
    }

    if (wave >= 2){
        #pragma unroll
        for (int mt = 0; mt < 4; mt++)
            #pragma unroll
            for (int nt = 0; nt < 4; nt++)
                #pragma unroll
                for (int r = 0; r < 4; r++)
                    red[wave-2][mt*16 + quad*4 + r][nt*16 + mr] = acc[mt][nt][r];
    }
    __syncthreads();
    if (wave < 2){
        #pragma unroll
        for (int mt = 0; mt < 4; mt++)
            #pragma unroll
            for (int nt = 0; nt < 4; nt++)
                #pragma unroll
                for (int r = 0; r < 4; r++)
                    acc[mt][nt][r] += red[wave][mt*16 + quad*4 + r][nt*16 + mr];
    }
    __syncthreads();
    if (wave == 1){
        #pragma unroll
        for (int mt = 0; mt < 4; mt++)
            #pragma unroll
            for (int nt = 0; nt < 4; nt++)
                #pragma unroll
                for (int r = 0; r < 4; r++)
                    red[0][mt*16 + quad*4 + r][nt*16 + mr] = acc[mt][nt][r];
    }
    __syncthreads();
    if (wave == 0){
        #pragma unroll
        for (int mt = 0; mt < 4; mt++){
            #pragma unroll
            for (int nt = 0; nt < 4; nt++){
                int n = n0 + nt*16 + mr;
                float bv = bias[n];
                #pragma unroll
                for (int r = 0; r < 4; r++){
                    int m = mt*16 + quad*4 + r;
                    float v = acc[mt][nt][r] + red[0][m][nt*16 + mr] + bv;
                    if (n < Hq) h0[(size_t)m*Hq + n] = __float2bfloat16(v);
                    else        c_state[(size_t)m*Hq + (n - Hq)] = v;
                }
            }
        }
    }
}

// ================= att1 GEMM (bf16 A, bf16 out) =================
__global__ __launch_bounds__(256)
void att1_gemm(const bf16_t* __restrict__ A, const bf16_t* __restrict__ W,
               const float* __restrict__ bias, bf16_t* __restrict__ C)
{
    const int lane = threadIdx.x & 63;
    const int wave = threadIdx.x >> 6;
    const int mr = lane & 15;
    const int quad = lane >> 4;
    const int m0 = blockIdx.x * 64;
    const int n0 = (blockIdx.y * 4 + wave) * 64;

    const bf16_t* ap[4];
    const bf16_t* bp[4];
    #pragma unroll
    for (int i = 0; i < 4; i++){
        ap[i] = A + (size_t)(m0 + i*16 + mr)*ENCq + quad*8;
        bp[i] = W + (size_t)(n0 + i*16 + mr)*ENCq + quad*8;
    }
    f32x4 zero = {0.f,0.f,0.f,0.f};
    f32x4 acc[4][4];
    #pragma unroll
    for (int i = 0; i < 4; i++)
        #pragma unroll
        for (int j = 0; j < 4; j++) acc[i][j] = zero;

    for (int k = 0; k < ENCq; k += 32){
        bf16x8 a[4], b[4];
        #pragma unroll
        for (int mt = 0; mt < 4; mt++) a[mt] = *(const bf16x8*)(ap[mt] + k);
        #pragma unroll
        for (int nt = 0; nt < 4; nt++) b[nt] = *(const bf16x8*)(bp[nt] + k);
        #pragma unroll
        for (int mt = 0; mt < 4; mt++)
            #pragma unroll
            for (int nt = 0; nt < 4; nt++)
                acc[mt][nt] = __builtin_amdgcn_mfma_f32_16x16x32_bf16(a[mt], b[nt], acc[mt][nt], 0, 0, 0);
    }
    #pragma unroll
    for (int mt = 0; mt < 4; mt++){
        #pragma unroll
        for (int nt = 0; nt < 4; nt++){
            int n = n0 + nt*16 + mr;
            float bv = bias[n];
            #pragma unroll
            for (int r = 0; r < 4; r++){
                int m = m0 + mt*16 + quad*4 + r;
                C[(size_t)m*Aq + n] = __float2bfloat16(acc[mt][nt][r] + bv);
            }
        }
    }
}

// ================= att2|gate GEMM: LDS-staged h, single K pass =================
// M=64, N=2560, K=512. grid 40 blocks x 256 thr; wave-tile 64 rows x 16 cols.
__global__ __launch_bounds__(256)
void attg_gemm(const bf16_t* __restrict__ h, const bf16_t* __restrict__ W,
               const float* __restrict__ bias, float* __restrict__ C)
{
    __shared__ __bf16 hs[64][520];
    {
        int r = threadIdx.x >> 2;
        int c0 = (threadIdx.x & 3) * 128;
        const bf16_t* src = h + (size_t)r*512 + c0;
        #pragma unroll
        for (int i = 0; i < 16; i++)
            *(bf16x8*)&hs[r][c0 + i*8] = *(const bf16x8*)(src + i*8);
    }
    __syncthreads();

    const int lane = threadIdx.x & 63;
    const int wave = threadIdx.x >> 6;
    const int mr = lane & 15;
    const int quad = lane >> 4;
    const int n0 = (blockIdx.x * 4 + wave) * 16;

    const bf16_t* bp = W + (size_t)(n0 + mr)*512 + quad*8;
    f32x4 zero = {0.f,0.f,0.f,0.f};
    f32x4 acc[4] = {zero, zero, zero, zero};

    #pragma unroll
    for (int kk = 0; kk < 16; kk++){
        bf16x8 b = *(const bf16x8*)(bp + kk*32);
        bf16x8 a[4];
        #pragma unroll
        for (int mt = 0; mt < 4; mt++)
            a[mt] = *(const bf16x8*)&hs[mt*16 + mr][kk*32 + quad*8];
        #pragma unroll
        for (int mt = 0; mt < 4; mt++)
            acc[mt] = __builtin_amdgcn_mfma_f32_16x16x32_bf16(a[mt], b, acc[mt], 0, 0, 0);
    }

    float bv = bias[n0 + mr];
    #pragma unroll
    for (int mt = 0; mt < 4; mt++){
        #pragma unroll
        for (int r = 0; r < 4; r++){
            int m = mt*16 + quad*4 + r;
            C[(size_t)m*2560 + n0 + mr] = acc[mt][r] + bv;
        }
    }
}

// ================= gates GEMM (K=3072, waves split K) fused with LSTM =================
__global__ __launch_bounds__(256)
void gates_lstm(const bf16_t* __restrict__ A, const bf16_t* __restrict__ W,
                const float* __restrict__ bias, float* __restrict__ c_state,
                bf16_t* __restrict__ h_next)
{
    __shared__ float red[2][64][64];
    const int lane = threadIdx.x & 63;
    const int wave = threadIdx.x >> 6;
    const int mr = lane & 15;
    const int quad = lane >> 4;
    const int n0 = blockIdx.x * 64;
    const int kw = 3072 >> 2;
    const int kbeg = wave * kw;

    const bf16_t* ap[4];
    const bf16_t* bp[4];
    #pragma unroll
    for (int i = 0; i < 4; i++){
        ap[i] = A + (size_t)(i*16 + mr)*3072 + quad*8;
        bp[i] = W + (size_t)(n0 + i*16 + mr)*3072 + quad*8;
    }
    f32x4 zero = {0.f,0.f,0.f,0.f};
    f32x4 acc[4][4];
    #pragma unroll
    for (int i = 0; i < 4; i++)
        #pragma unroll
        for (int j = 0; j < 4; j++) acc[i][j] = zero;

    for (int k = kbeg; k < kbeg + kw; k += 32){
        bf16x8 a[4], b[4];
        #pragma unroll
        for (int mt = 0; mt < 4; mt++) a[mt] = *(const bf16x8*)(ap[mt] + k);
        #pragma unroll
        for (int nt = 0; nt < 4; nt++) b[nt] = *(const bf16x8*)(bp[nt] + k);
        #pragma unroll
        for (int mt = 0; mt < 4; mt++)
            #pragma unroll
            for (int nt = 0; nt < 4; nt++)
                acc[mt][nt] = __builtin_amdgcn_mfma_f32_16x16x32_bf16(a[mt], b[nt], acc[mt][nt], 0, 0, 0);
    }

    if (wave >= 2){
        #pragma unroll
        for (int mt = 0; mt < 4; mt++)
            #pragma unroll
            for (int nt = 0; nt < 4; nt++)
                #pragma unroll
                for (int r = 0; r < 4; r++)
                    red[wave-2][mt*16 + quad*4 + r][nt*16 + mr] = acc[mt][nt][r];
    }
    __syncthreads();
    if (wave < 2){
        #pragma unroll
        for (int mt = 0; mt < 4; mt++)
            #pragma unroll
            for (int nt = 0; nt < 4; nt++)
                #pragma unroll
                for (int r = 0; r < 4; r++)
                    acc[mt][nt][r] += red[wave][mt*16 + quad*4 + r][nt*16 + mr];
    }
    __syncthreads();
    if (wave == 1){
        #pragma unroll
        for (int mt = 0; mt < 4; mt++)
            #pragma unroll
            for (int nt = 0; nt < 4; nt++)
                #pragma unroll
                for (int r = 0; r < 4; r++)
                    red[0][mt*16 + quad*4 + r][nt*16 + mr] = acc[mt][nt][r];
    }
    __syncthreads();
    if (wave == 0){
        #pragma unroll
        for (int mt = 0; mt < 4; mt++){
            #pragma unroll
            for (int nt = 0; nt < 4; nt++){
                int nl = nt*16 + mr;
                float bv = bias[n0 + nl];
                #pragma unroll
                for (int r = 0; r < 4; r++){
                    int m = mt*16 + quad*4 + r;
                    float v = acc[mt][nt][r] + red[0][m][nl] + bv;
                    red[0][m][nl] = v;   // same lane read+write: safe
                }
            }
        }
    }
    __syncthreads();
    // LSTM elementwise on this block's 16 hidden units x 64 batch
    #pragma unroll
    for (int q = 0; q < 4; q++){
        int idx = threadIdx.x + 256*q;
        int m = idx & 63;
        int jl = idx >> 6;
        int j = (n0 >> 2) + jl;
        float gi = sigmoidf_(red[0][m][4*jl + 0]);
        float gf = sigmoidf_(red[0][m][4*jl + 1]);
        float gg = tanhf(red[0][m][4*jl + 2]);
        float go = sigmoidf_(red[0][m][4*jl + 3]);
        float c  = c_state[m*512 + j];
        float cn = gf*c + gi*gg;
        float hn = go * tanhf(cn);
        c_state[m*512 + j] = cn;
        h_next[m*512 + j] = __float2bfloat16(hn);
    }
}

// ================= batched preds GEMM over all 29 steps =================
// A = h_hist slots 1..29 as rows m = t*64+b (M=1856), W = fc_w bf16, N=30000, K=512.
// grid (8, 469) x 256 thr; block tile 256 rows x 64 cols; wave w: rows +w*64.
__global__ __launch_bounds__(256)
void preds_batched(const bf16_t* __restrict__ Ah, const bf16_t* __restrict__ W,
                   const float* __restrict__ bias, float* __restrict__ C,
                   const int* __restrict__ dec_len)
{
    const int lane = threadIdx.x & 63;
    const int wave = threadIdx.x >> 6;
    const int mr = lane & 15;
    const int quad = lane >> 4;
    const int m0 = blockIdx.x * 256 + wave * 64;
    const int n0 = blockIdx.y * 64;

    const bf16_t* ap[4];
    const bf16_t* bp[4];
    #pragma unroll
    for (int i = 0; i < 4; i++){
        int row = m0 + i*16 + mr; if (row > 1855) row = 1855;
        ap[i] = Ah + (size_t)row*512 + quad*8;
        int n = n0 + i*16 + mr;   if (n > Vq-1) n = Vq-1;
        bp[i] = W + (size_t)n*512 + quad*8;
    }
    f32x4 zero = {0.f,0.f,0.f,0.f};
    f32x4 acc[4][4];
    #pragma unroll
    for (int i = 0; i < 4; i++)
        #pragma unroll
        for (int j = 0; j < 4; j++) acc[i][j] = zero;

    #pragma unroll
    for (int kk = 0; kk < 16; kk++){
        bf16x8 a[4], b[4];
        #pragma unroll
        for (int mt = 0; mt < 4; mt++) a[mt] = *(const bf16x8*)(ap[mt] + kk*32);
        #pragma unroll
        for (int nt = 0; nt < 4; nt++) b[nt] = *(const bf16x8*)(bp[nt] + kk*32);
        #pragma unroll
        for (int mt = 0; mt < 4; mt++)
            #pragma unroll
            for (int nt = 0; nt < 4; nt++)
                acc[mt][nt] = __builtin_amdgcn_mfma_f32_16x16x32_bf16(a[mt], b[nt], acc[mt][nt], 0, 0, 0);
    }

    #pragma unroll
    for (int mt = 0; mt < 4; mt++){
        #pragma unroll
        for (int r = 0; r < 4; r++){
            int m = m0 + mt*16 + quad*4 + r;
            if (m >= 1856) continue;
            int tt = m >> 6, b = m & 63;
            bool msk = (tt >= dec_len[b]);
            float* crow = C + (size_t)b*(Tq*Vq) + (size_t)tt*Vq;
            #pragma unroll
            for (int nt = 0; nt < 4; nt++){
                int n = n0 + nt*16 + mr;
                if (n < Vq){
                    float v = acc[mt][nt][r] + bias[n];
                    crow[n] = msk ? 0.f : v;
                }
            }
        }
    }
}

// ---------------- attention scores + softmax (one block per sorted b) ----------------
__global__ __launch_bounds__(256)
void attn_kernel(const bf16_t* __restrict__ att1,
                 const float* __restrict__ att2gate,
                 const float* __restrict__ faw, const float* __restrict__ fab,
                 const int* __restrict__ dec_len,
                 float* __restrict__ alpha_ws,
                 float* __restrict__ alphas_out, int t)
{
    __shared__ float es[Pq];
    __shared__ float red[8];
    int b = blockIdx.x;
    int tid = threadIdx.x;
    int wid = tid >> 6, lane = tid & 63;

    float a2r[8], fwr[8];
    {
        const float4* a2p = (const float4*)(att2gate + (size_t)b*2560);
        const float4* fwp = (const float4*)faw;
        float4 u0 = a2p[lane*2], u1 = a2p[lane*2+1];
        float4 w0 = fwp[lane*2], w1 = fwp[lane*2+1];
        a2r[0]=u0.x; a2r[1]=u0.y; a2r[2]=u0.z; a2r[3]=u0.w;
        a2r[4]=u1.x; a2r[5]=u1.y; a2r[6]=u1.z; a2r[7]=u1.w;
        fwr[0]=w0.x; fwr[1]=w0.y; fwr[2]=w0.z; fwr[3]=w0.w;
        fwr[4]=w1.x; fwr[5]=w1.y; fwr[6]=w1.z; fwr[7]=w1.w;
    }
    float fb = fab[0];
    const bf16_t* a1b = att1 + (size_t)b * Pq * Aq + lane*8;
    for (int p = wid; p < Pq; p += 4){
        bf16x8 rv = *(const bf16x8*)(a1b + (size_t)p * Aq);
        float s = 0.f;
        #pragma unroll
        for (int i = 0; i < 8; i++){
            float v = (float)rv[i] + a2r[i];
            v = v > 0.f ? v : 0.f;
            s += v * fwr[i];
        }
        #pragma unroll
        for (int off = 32; off; off >>= 1) s += __shfl_xor(s, off);
        if (lane == 0) es[p] = s + fb;
    }
    __syncthreads();
    float v = (tid < Pq) ? es[tid] : -3.4e38f;
    float m = v;
    #pragma unroll
    for (int off = 32; off; off >>= 1) m = fmaxf(m, __shfl_xor(m, off));
    if ((tid & 63) == 0) red[tid >> 6] = m;
    __syncthreads();
    float bm = fmaxf(fmaxf(red[0], red[1]), fmaxf(red[2], red[3]));
    float ex = (tid < Pq) ? expf(v - bm) : 0.f;
    float s = ex;
    #pragma unroll
    for (int off = 32; off; off >>= 1) s += __shfl_xor(s, off);
    if ((tid & 63) == 0) red[4 + (tid >> 6)] = s;
    __syncthreads();
    float bs = red[4] + red[5] + red[6] + red[7];
    if (tid < Pq){
        float al = ex / bs;
        alpha_ws[b*Pq + tid] = al;
        float mask = (t < dec_len[b]) ? 1.f : 0.f;
        alphas_out[((size_t)b*Tq + t)*Pq + tid] = al * mask;
    }
}

// ---------------- awe = gate * (alpha @ enc_bf), builds bf16 x_cat = [emb | awe | h] ----------------
__global__ __launch_bounds__(256)
void awe_xcat_kernel(const bf16_t* __restrict__ enc_bf,
                     const float* __restrict__ att2gate,
                     const float* __restrict__ alpha_ws,
                     const float* __restrict__ embed,
                     const bf16_t* __restrict__ h_prev,
                     const int* __restrict__ caps_sorted,
                     bf16_t* __restrict__ xcat, int t)
{
    int b = blockIdx.x, y = blockIdx.y, tid = threadIdx.x;
    __shared__ float als[Pq];
    if (tid < Pq) als[tid] = alpha_ws[b*Pq + tid];
    __syncthreads();
    int d = y*256 + tid;
    const bf16_t* ebase = enc_bf + (size_t)b * Pq * ENCq + d;
    float s = 0.f;
    for (int p = 0; p < Pq; p++) s += als[p] * (float)ebase[(size_t)p*ENCq];
    float g = sigmoidf_(att2gate[(size_t)b*2560 + 512 + d]);
    xcat[(size_t)b*3072 + 512 + d] = __float2bfloat16(g * s);
    if (y == 0){
        int cap = caps_sorted[b*Lq + t];
        const float* er = embed + (size_t)cap*512;
        for (int j = tid; j < 512; j += 256) xcat[(size_t)b*3072 + j] = __float2bfloat16(er[j]);
    } else if (y == 1){
        for (int j = tid; j < Hq; j += 256) xcat[(size_t)b*3072 + 2560 + j] = h_prev[b*512 + j];
    }
}

extern "C" void kernel_launch(void* const* d_in, const int* in_sizes, int n_in,
                              void* d_out, int out_size, void* d_ws, size_t ws_size,
                              hipStream_t stream)
{
    const float* encoder_out = (const float*)d_in[0];
    const float* enc_att_w   = (const float*)d_in[1];
    const float* enc_att_b   = (const float*)d_in[2];
    const float* dec_att_w   = (const float*)d_in[3];
    const float* dec_att_b   = (const float*)d_in[4];
    const float* full_att_w  = (const float*)d_in[5];
    const float* full_att_b  = (const float*)d_in[6];
    const float* embed       = (const float*)d_in[7];
    const float* W_ih        = (const float*)d_in[8];
    const float* W_hh        = (const float*)d_in[9];
    const float* b_ih        = (const float*)d_in[10];
    const float* b_hh        = (const float*)d_in[11];
    const float* init_h_w    = (const float*)d_in[12];
    const float* init_h_b    = (const float*)d_in[13];
    const float* init_c_w    = (const float*)d_in[14];
    const float* init_c_b    = (const float*)d_in[15];
    const float* f_beta_w    = (const float*)d_in[16];
    const float* f_beta_b    = (const float*)d_in[17];
    const float* fc_w        = (const float*)d_in[18];
    const float* fc_b        = (const float*)d_in[19];
    const int*   enc_caps    = (const int*)d_in[20];
    const int*   cap_len     = (const int*)d_in[21];

    float* out_preds   = (float*)d_out;
    float* out_caps    = out_preds + (size_t)Bq*Tq*Vq;
    float* out_declen  = out_caps + Bq*Lq;
    float* out_alphas  = out_declen + Bq;
    float* out_sortind = out_alphas + (size_t)Bq*Tq*Pq;

    char* cur = (char*)d_ws;
    auto alloc = [&](size_t bytes) -> char* {
        char* p = cur;
        cur += (bytes + 255) & ~(size_t)255;
        return p;
    };
    bf16_t* enc_bf    = (bf16_t*)alloc((size_t)12544*2048*2);
    bf16_t* att1_bf   = (bf16_t*)alloc((size_t)12544*512*2);
    bf16_t* fcw_bf    = (bf16_t*)alloc((size_t)30000*512*2);
    bf16_t* wcatg_bf  = (bf16_t*)alloc((size_t)2048*3072*2);
    bf16_t* whc_bf    = (bf16_t*)alloc((size_t)1024*2048*2);
    bf16_t* wcat2_bf  = (bf16_t*)alloc((size_t)2560*512*2);
    bf16_t* encattw_bf= (bf16_t*)alloc((size_t)512*2048*2);
    bf16_t* meanenc_bf= (bf16_t*)alloc((size_t)64*2048*2);
    bf16_t* h_hist    = (bf16_t*)alloc((size_t)30*64*512*2);   // slot 0 = h0, slot t+1 = h after step t
    bf16_t* xcat_bf   = (bf16_t*)alloc((size_t)64*3072*2);
    float* c_state   = (float*)alloc((size_t)64*512*4);
    float* att2gate  = (float*)alloc((size_t)64*2560*4);
    float* bias_hc   = (float*)alloc(1024*4);
    float* bias2     = (float*)alloc(2560*4);
    float* bias_g    = (float*)alloc(2048*4);
    float* alpha_ws  = (float*)alloc((size_t)64*196*4);
    int* caps_sorted = (int*)alloc(Bq*Lq*4);
    int* sort_ind_i  = (int*)alloc(64*4);
    int* dec_len_i   = (int*)alloc(64*4);

    // ---- setup ----
    sort_kernel<<<1, 64, 0, stream>>>(cap_len, enc_caps, sort_ind_i, dec_len_i,
                                      caps_sorted, out_caps, out_declen, out_sortind);

    cvt_bf16<<<(1048576+255)/256, 256, 0, stream>>>(encattw_bf, enc_att_w, 1048576);
    cvt_bf16<<<(15360000+255)/256, 256, 0, stream>>>(fcw_bf, fc_w, 15360000);
    pack_rowcat_bf16<<<(2097152+255)/256, 256, 0, stream>>>(whc_bf, init_h_w, 1048576, init_c_w, 1048576);
    pack_rowcat_bf16<<<(1310720+255)/256, 256, 0, stream>>>(wcat2_bf, dec_att_w, 262144, f_beta_w, 1048576);
    pack_colcat_perm_bf16<<<(6291456+255)/256, 256, 0, stream>>>(wcatg_bf, W_ih, W_hh);
    pack_rowcat_f32<<<(1024+255)/256, 256, 0, stream>>>(bias_hc, init_h_b, 512, init_c_b, 512);
    pack_rowcat_f32<<<(2560+255)/256, 256, 0, stream>>>(bias2, dec_att_b, 512, f_beta_b, 2048);
    biasg_perm_kernel<<<8, 256, 0, stream>>>(bias_g, b_ih, b_hh);

    gather_cvt_mean<<<dim3(64,8), 256, 0, stream>>>(encoder_out, sort_ind_i, enc_bf, meanenc_bf);

    // h0/c0: M=64, N=1024, K=2048
    hc0_ksplit<<<16, 256, 0, stream>>>(meanenc_bf, whc_bf, bias_hc, h_hist, c_state);

    // att1: M=12544 (sorted), N=512, K=2048
    att1_gemm<<<dim3(196,2), 256, 0, stream>>>(enc_bf, encattw_bf, enc_att_b, att1_bf);

    for (int t = 0; t < Tq; t++){
        const bf16_t* h_prev = h_hist + (size_t)t*Bq*Hq;
        bf16_t* h_next = h_hist + (size_t)(t+1)*Bq*Hq;

        attg_gemm<<<40, 256, 0, stream>>>(h_prev, wcat2_bf, bias2, att2gate);

        attn_kernel<<<64, 256, 0, stream>>>(att1_bf, att2gate, full_att_w, full_att_b,
                                            dec_len_i, alpha_ws, out_alphas, t);

        awe_xcat_kernel<<<dim3(64,8), 256, 0, stream>>>(enc_bf, att2gate, alpha_ws, embed,
                                                        h_prev, caps_sorted, xcat_bf, t);

        gates_lstm<<<32, 256, 0, stream>>>(xcat_bf, wcatg_bf, bias_g, c_state, h_next);
    }

    // batched preds over all 29 steps: M=1856, N=30000, K=512
    preds_batched<<<dim3(8,469), 256, 0, stream>>>(h_hist + (size_t)Bq*Hq, fcw_bf, fc_b,
                                                   out_preds, dec_len_i);
}